// Round 1
// baseline (839.349 us; speedup 1.0000x reference)
//
#include <hip/hip_runtime.h>

#define S_LEN 2048
#define NB    2
#define NH    16
#define NKV   4
#define HDIM  256
#define LW    10752   // Ycat row width: 8192 (q|gate) + 1024 (k) + 1024 (v) + 512 (r)

using bf16x8 = __attribute__((ext_vector_type(8))) short;
using s16x4  = __attribute__((ext_vector_type(4))) short;
using f32x4  = __attribute__((ext_vector_type(4))) float;

__device__ __forceinline__ float bf2f(short u){
  union { float f; unsigned u; } x; x.u = ((unsigned)(unsigned short)u) << 16; return x.f;
}
__device__ __forceinline__ short f2bf(float f){
  unsigned i = __builtin_bit_cast(unsigned, f);
  unsigned r = (i + 0x7fffu + ((i >> 16) & 1u)) >> 16;
  return (short)r;
}
__device__ __forceinline__ float sigm(float x){ return 1.0f / (1.0f + __expf(-x)); }

#if defined(__has_builtin)
#  if __has_builtin(__builtin_amdgcn_global_load_lds)
#    define USE_GLL 1
#  endif
#endif
#ifndef USE_GLL
#  define USE_GLL 0
#endif

#if USE_GLL
__device__ __forceinline__ void gload16(const short* g, short* lds){
  __builtin_amdgcn_global_load_lds((const __attribute__((address_space(1))) void*)g,
                                   (__attribute__((address_space(3))) void*)lds,
                                   16, 0, 0);
}
#endif

// ---------------- f32 -> bf16 elementwise ----------------
__global__ void k_cvt(const float* __restrict__ in, short* __restrict__ out, int n4){
  int i = blockIdx.x * blockDim.x + threadIdx.x;
  if (i >= n4) return;
  float4 v = ((const float4*)in)[i];
  s16x4 o;
  o[0] = f2bf(v.x); o[1] = f2bf(v.y); o[2] = f2bf(v.z); o[3] = f2bf(v.w);
  ((s16x4*)out)[i] = o;
}

// ---------------- f32 (R,C) -> bf16 (C,R) transpose+convert ----------------
__global__ void k_tcvt(const float* __restrict__ in, short* __restrict__ out, int R, int C){
  __shared__ float tile[32][33];
  int c0 = blockIdx.x * 32, r0 = blockIdx.y * 32;
  int tx = threadIdx.x, ty = threadIdx.y;   // (32, 8)
  #pragma unroll
  for (int i = ty; i < 32; i += 8)
    tile[i][tx] = in[(size_t)(r0 + i) * C + c0 + tx];
  __syncthreads();
  #pragma unroll
  for (int i = ty; i < 32; i += 8)
    out[(size_t)(c0 + i) * R + r0 + tx] = f2bf(tile[tx][i]);
}

// ---------------- bf16 V-slice transpose: Ycat v -> VT[b,hk,d,s] ----------------
__global__ void k_vt(const short* __restrict__ Ycat, short* __restrict__ VT){
  __shared__ short tile[32][33];
  int b = blockIdx.z >> 2, hk = blockIdx.z & 3;
  int s0 = blockIdx.x * 32, d0 = blockIdx.y * 32;
  int tx = threadIdx.x, ty = threadIdx.y;   // (32, 8)
  #pragma unroll
  for (int i = ty; i < 32; i += 8)
    tile[i][tx] = Ycat[(size_t)(b * S_LEN + s0 + i) * LW + 9216 + hk * 256 + d0 + tx];
  __syncthreads();
  #pragma unroll
  for (int i = ty; i < 32; i += 8)
    VT[(size_t)((b * NKV + hk) * HDIM + d0 + i) * S_LEN + s0 + tx] = tile[tx][i];
}

// ---------------- bf16 GEMM, BT form (m97 structure) ----------------
// C[M,N] = A[M,K] * BT[N,K]^T ; 128x128 tile, BK=32, 4 waves, fp32 accum
template<int OUTF32>
__global__ __launch_bounds__(256) void k_gemm(const short* __restrict__ A,
                                              const short* __restrict__ BT,
                                              void* __restrict__ C,
                                              int M, int N, int K)
{
  __shared__ __align__(16) short As[128 * 32];
  __shared__ __align__(16) short Bs[128 * 32];
  const int t = threadIdx.x, lane = t & 63, w = t >> 6;
  const int wr = w >> 1, wc = w & 1;
  const int m0 = blockIdx.y * 128, n0 = blockIdx.x * 128;
  f32x4 acc[4][4] = {};
  for (int k0 = 0; k0 < K; k0 += 32) {
#if USE_GLL
    #pragma unroll
    for (int c = 0; c < 2; ++c) {
      gload16(A  + (size_t)(m0 + c*64 + w*16 + (lane >> 2)) * K + k0 + (lane & 3) * 8,
              As + c*2048 + w*512);
      gload16(BT + (size_t)(n0 + c*64 + w*16 + (lane >> 2)) * K + k0 + (lane & 3) * 8,
              Bs + c*2048 + w*512);
    }
#else
    #pragma unroll
    for (int i = 0; i < 2; ++i) {
      int id = i * 256 + t;
      int row = id >> 2, cc = id & 3;
      *(int4*)&As[row*32 + cc*8] = *(const int4*)&A [(size_t)(m0 + row) * K + k0 + cc*8];
      *(int4*)&Bs[row*32 + cc*8] = *(const int4*)&BT[(size_t)(n0 + row) * K + k0 + cc*8];
    }
#endif
    __syncthreads();
    bf16x8 af[4], bfr[4];
    #pragma unroll
    for (int i = 0; i < 4; ++i) {
      af[i]  = *(const bf16x8*)&As[(wr*64 + i*16 + (lane & 15)) * 32 + (lane >> 4) * 8];
      bfr[i] = *(const bf16x8*)&Bs[(wc*64 + i*16 + (lane & 15)) * 32 + (lane >> 4) * 8];
    }
    #pragma unroll
    for (int i = 0; i < 4; ++i)
      #pragma unroll
      for (int j = 0; j < 4; ++j)
        acc[i][j] = __builtin_amdgcn_mfma_f32_16x16x32_bf16(af[i], bfr[j], acc[i][j], 0, 0, 0);
    __syncthreads();
  }
  #pragma unroll
  for (int i = 0; i < 4; ++i)
    #pragma unroll
    for (int r = 0; r < 4; ++r) {
      int row = m0 + wr*64 + i*16 + (lane >> 4) * 4 + r;
      #pragma unroll
      for (int j = 0; j < 4; ++j) {
        int col = n0 + wc*64 + j*16 + (lane & 15);
        float v = acc[i][j][r];
        if (OUTF32) ((float*)C)[(size_t)row * N + col] = v;
        else        ((short*)C)[(size_t)row * N + col] = f2bf(v);
      }
    }
}

// ---------------- per-token: RMSNorm(q,k), gates, partial RoPE, in place ----------------
__global__ __launch_bounds__(256) void k_post(short* __restrict__ Ycat,
    const float* __restrict__ cosb, const float* __restrict__ sinb,
    const float* __restrict__ qw, const float* __restrict__ kw)
{
  const int tok = blockIdx.x;                 // b*S + s
  const int lane = threadIdx.x & 63, w = threadIdx.x >> 6;
  const size_t rowb = (size_t)tok * LW;
  const int d0 = lane * 4;

  float gq[4], gv[4];
  {
    s16x4 a  = *(const s16x4*)&Ycat[rowb + 10240 + d0];
    s16x4 bq = *(const s16x4*)&Ycat[rowb + 10240 + 256 + d0];
    #pragma unroll
    for (int j = 0; j < 4; ++j){ gq[j] = sigm(bf2f(a[j])); gv[j] = sigm(bf2f(bq[j])); }
  }
  float c4[4] = {0,0,0,0}, s4[4] = {0,0,0,0};
  if (lane < 16) {
    float4 c = *(const float4*)&cosb[(size_t)tok * 64 + d0];
    float4 s = *(const float4*)&sinb[(size_t)tok * 64 + d0];
    c4[0]=c.x; c4[1]=c.y; c4[2]=c.z; c4[3]=c.w;
    s4[0]=s.x; s4[1]=s.y; s4[2]=s.z; s4[3]=s.w;
  }
  float4 qv4 = *(const float4*)&qw[d0];
  float4 kv4 = *(const float4*)&kw[d0];
  float qwa[4] = {qv4.x, qv4.y, qv4.z, qv4.w};
  float kwa[4] = {kv4.x, kv4.y, kv4.z, kv4.w};

  // 16 q-heads: wave w handles heads 4w..4w+3
  #pragma unroll
  for (int hi = 0; hi < 4; ++hi) {
    const int hh = w * 4 + hi;
    const size_t off = rowb + hh * 512 + d0;
    s16x4 v = *(const s16x4*)&Ycat[off];
    float x[4];
    #pragma unroll
    for (int j = 0; j < 4; ++j) x[j] = bf2f(v[j]);
    float ss = x[0]*x[0] + x[1]*x[1] + x[2]*x[2] + x[3]*x[3];
    #pragma unroll
    for (int o2 = 1; o2 < 64; o2 <<= 1) ss += __shfl_xor(ss, o2);
    float rr = rsqrtf(ss * (1.0f/256.0f) + 1e-6f);
    #pragma unroll
    for (int j = 0; j < 4; ++j) x[j] = x[j] * rr * (1.0f + qwa[j]) * gq[j];
    float p[4];
    #pragma unroll
    for (int j = 0; j < 4; ++j) p[j] = __shfl_xor(x[j], 8);
    if (lane < 8)       { for (int j = 0; j < 4; ++j) x[j] = x[j]*c4[j] - p[j]*s4[j]; }
    else if (lane < 16) { for (int j = 0; j < 4; ++j) x[j] = x[j]*c4[j] + p[j]*s4[j]; }
    s16x4 o;
    #pragma unroll
    for (int j = 0; j < 4; ++j) o[j] = f2bf(x[j]);
    *(s16x4*)&Ycat[off] = o;
  }
  // k-head (wave w <-> kv head w)
  {
    const size_t off = rowb + 8192 + w * 256 + d0;
    s16x4 v = *(const s16x4*)&Ycat[off];
    float x[4];
    #pragma unroll
    for (int j = 0; j < 4; ++j) x[j] = bf2f(v[j]);
    float ss = x[0]*x[0] + x[1]*x[1] + x[2]*x[2] + x[3]*x[3];
    #pragma unroll
    for (int o2 = 1; o2 < 64; o2 <<= 1) ss += __shfl_xor(ss, o2);
    float rr = rsqrtf(ss * (1.0f/256.0f) + 1e-6f);
    #pragma unroll
    for (int j = 0; j < 4; ++j) x[j] = x[j] * rr * (1.0f + kwa[j]) * gq[j];
    float p[4];
    #pragma unroll
    for (int j = 0; j < 4; ++j) p[j] = __shfl_xor(x[j], 8);
    if (lane < 8)       { for (int j = 0; j < 4; ++j) x[j] = x[j]*c4[j] - p[j]*s4[j]; }
    else if (lane < 16) { for (int j = 0; j < 4; ++j) x[j] = x[j]*c4[j] + p[j]*s4[j]; }
    s16x4 o;
    #pragma unroll
    for (int j = 0; j < 4; ++j) o[j] = f2bf(x[j]);
    *(s16x4*)&Ycat[off] = o;
  }
  // v-head
  {
    const size_t off = rowb + 9216 + w * 256 + d0;
    s16x4 v = *(const s16x4*)&Ycat[off];
    s16x4 o;
    #pragma unroll
    for (int j = 0; j < 4; ++j) o[j] = f2bf(bf2f(v[j]) * gv[j]);
    *(s16x4*)&Ycat[off] = o;
  }
}

// ---------------- flash attention, causal, GQA; fused *sigmoid(gate) ----------------
// grid (S/64, NH, B), 256 thr = 4 waves. QBLK=64 (wave w owns q-rows w*16..+15 for QK),
// KVBLK=32. O split by d across waves (wave w: d in [w*64, w*64+64)).
__global__ __launch_bounds__(256) void k_attn(const short* __restrict__ Ycat,
                                              const short* __restrict__ VT,
                                              short* __restrict__ AO)
{
  __shared__ __align__(16) short Ks[32 * 264];
  __shared__ __align__(16) short Vs[256 * 40];
  __shared__ __align__(16) short Ps[64 * 40];
  __shared__ float redLds[64];

  const int t = threadIdx.x, lane = t & 63, w = t >> 6;
  const int q0 = blockIdx.x * 64;
  const int h  = blockIdx.y;
  const int b  = blockIdx.z;
  const int hk = h >> 2;

  // preload Q fragments for this wave's 16 q-rows (registers, reused all tiles)
  bf16x8 qf[8];
  {
    const size_t qb = ((size_t)(b * S_LEN) + q0 + w*16 + (lane & 15)) * LW
                    + h * 512 + ((lane >> 4) * 8);
    #pragma unroll
    for (int kk = 0; kk < 8; ++kk)
      qf[kk] = *(const bf16x8*)&Ycat[qb + kk * 32];
  }

  f32x4 oacc[4][4] = {};
  float m_r[4], l_r[4];
  #pragma unroll
  for (int r = 0; r < 4; ++r){ m_r[r] = -1e30f; l_r[r] = 0.0f; }

  const int jend = q0 + 64;
  for (int j0 = 0; j0 < jend; j0 += 32) {
    // stage K tile (32 x 256) and V^T tile (256 x 32)
    #pragma unroll
    for (int i = 0; i < 4; ++i) {
      int id = i * 256 + t;
      int row = id >> 5, c = id & 31;
      *(int4*)&Ks[row * 264 + c * 8] =
        *(const int4*)&Ycat[((size_t)(b * S_LEN) + j0 + row) * LW + 8192 + hk * 256 + c * 8];
    }
    #pragma unroll
    for (int i = 0; i < 4; ++i) {
      int id = i * 256 + t;
      int d = id >> 2, c = id & 3;
      *(int4*)&Vs[d * 40 + c * 8] =
        *(const int4*)&VT[((size_t)((b * NKV + hk) * HDIM + d)) * S_LEN + j0 + c * 8];
    }
    __syncthreads();

    // QK^T for this wave's 16 rows x 32 keys
    f32x4 sa0 = {}, sa1 = {};
    #pragma unroll
    for (int kk = 0; kk < 8; ++kk) {
      bf16x8 b0 = *(const bf16x8*)&Ks[(lane & 15) * 264 + kk*32 + (lane >> 4) * 8];
      bf16x8 b1 = *(const bf16x8*)&Ks[(16 + (lane & 15)) * 264 + kk*32 + (lane >> 4) * 8];
      sa0 = __builtin_amdgcn_mfma_f32_16x16x32_bf16(qf[kk], b0, sa0, 0, 0, 0);
      sa1 = __builtin_amdgcn_mfma_f32_16x16x32_bf16(qf[kk], b1, sa1, 0, 0, 0);
    }

    // online softmax (rows replicated across the 16 lanes of each lane&15 group)
    #pragma unroll
    for (int r = 0; r < 4; ++r) {
      const int qrow = w*16 + (lane >> 4) * 4 + r;
      const int qg = q0 + qrow;
      float s0 = sa0[r] * 0.0625f;
      float s1 = sa1[r] * 0.0625f;
      if (j0 + (lane & 15) > qg)       s0 = -1e9f;
      if (j0 + 16 + (lane & 15) > qg)  s1 = -1e9f;
      float mx = fmaxf(s0, s1);
      #pragma unroll
      for (int off = 1; off < 16; off <<= 1) mx = fmaxf(mx, __shfl_xor(mx, off));
      float mnew  = fmaxf(m_r[r], mx);
      float alpha = __expf(m_r[r] - mnew);
      float p0 = __expf(s0 - mnew);
      float p1 = __expf(s1 - mnew);
      float rs = p0 + p1;
      #pragma unroll
      for (int off = 1; off < 16; off <<= 1) rs += __shfl_xor(rs, off);
      l_r[r] = alpha * l_r[r] + rs;
      m_r[r] = mnew;
      if ((lane & 15) == 0) redLds[qrow] = alpha;
      Ps[qrow * 40 + (lane & 15)]      = f2bf(p0);
      Ps[qrow * 40 + 16 + (lane & 15)] = f2bf(p1);
    }
    __syncthreads();

    // rescale O by alpha, then PV
    #pragma unroll
    for (int i = 0; i < 4; ++i)
      #pragma unroll
      for (int r = 0; r < 4; ++r) {
        float a = redLds[i*16 + (lane >> 4) * 4 + r];
        #pragma unroll
        for (int j = 0; j < 4; ++j) oacc[i][j][r] *= a;
      }
    bf16x8 pa[4], vb[4];
    #pragma unroll
    for (int i = 0; i < 4; ++i)
      pa[i] = *(const bf16x8*)&Ps[(i*16 + (lane & 15)) * 40 + (lane >> 4) * 8];
    #pragma unroll
    for (int j = 0; j < 4; ++j)
      vb[j] = *(const bf16x8*)&Vs[(w*64 + j*16 + (lane & 15)) * 40 + (lane >> 4) * 8];
    #pragma unroll
    for (int i = 0; i < 4; ++i)
      #pragma unroll
      for (int j = 0; j < 4; ++j)
        oacc[i][j] = __builtin_amdgcn_mfma_f32_16x16x32_bf16(pa[i], vb[j], oacc[i][j], 0, 0, 0);
    __syncthreads();
  }

  // publish denominators
  if ((lane & 15) == 0) {
    #pragma unroll
    for (int r = 0; r < 4; ++r)
      redLds[w*16 + (lane >> 4) * 4 + r] = l_r[r];
  }
  __syncthreads();

  // epilogue: O/l * sigmoid(gate) -> AO[b,s, h*256+d] (bf16)
  #pragma unroll
  for (int i = 0; i < 4; ++i)
    #pragma unroll
    for (int r = 0; r < 4; ++r) {
      int row = i*16 + (lane >> 4) * 4 + r;
      float linv = 1.0f / redLds[row];
      int qg = q0 + row;
      size_t gb = ((size_t)(b * S_LEN) + qg) * LW + h * 512 + 256;
      size_t ob = ((size_t)(b * S_LEN) + qg) * 4096 + h * 256;
      #pragma unroll
      for (int j = 0; j < 4; ++j) {
        int d = w*64 + j*16 + (lane & 15);
        float g = sigm(bf2f(Ycat[gb + d]));
        AO[ob + d] = f2bf(oacc[i][j][r] * linv * g);
      }
    }
}

extern "C" void kernel_launch(void* const* d_in, const int* in_sizes, int n_in,
                              void* d_out, int out_size, void* d_ws, size_t ws_size,
                              hipStream_t stream) {
  const float* X    = (const float*)d_in[0];
  const float* cosb = (const float*)d_in[1];
  const float* sinb = (const float*)d_in[2];
  // d_in[3] = attention_mask: exactly causal, re-derived in-kernel
  const float* Wq   = (const float*)d_in[4];
  const float* Wk   = (const float*)d_in[5];
  const float* Wv   = (const float*)d_in[6];
  const float* Wo   = (const float*)d_in[7];
  const float* qw   = (const float*)d_in[8];
  const float* kw   = (const float*)d_in[9];
  const float* Wr   = (const float*)d_in[10];

  // workspace layout (shorts). AO aliases WcatT (dead after the first GEMM).
  short* Xb    = (short*)d_ws;                       //  8,388,608
  short* WcatT = Xb    +  8388608;                   // 22,020,096 = [WqT|WkT|WvT|WrT] rows x K=2048
  short* AO    = WcatT;                              // 16,777,216 (alias, used post-GEMM1)
  short* WoT   = WcatT + 22020096;                   //  8,388,608
  short* Ycat  = WoT   +  8388608;                   // 44,040,192
  short* VT    = Ycat  + 44040192;                   //  4,194,304
  // total = 174,063,616 bytes

  dim3 tb(32, 8);
  k_cvt<<<8192, 256, 0, stream>>>(X, Xb, 2097152);
  k_tcvt<<<dim3(256, 64), tb, 0, stream>>>(Wq, WcatT,                      2048, 8192);
  k_tcvt<<<dim3( 32, 64), tb, 0, stream>>>(Wk, WcatT + (size_t)8192*2048,  2048, 1024);
  k_tcvt<<<dim3( 32, 64), tb, 0, stream>>>(Wv, WcatT + (size_t)9216*2048,  2048, 1024);
  k_tcvt<<<dim3( 16, 64), tb, 0, stream>>>(Wr, WcatT + (size_t)10240*2048, 2048,  512);
  k_tcvt<<<dim3( 64,128), tb, 0, stream>>>(Wo, WoT,                        4096, 2048);

  k_gemm<0><<<dim3(84, 32), 256, 0, stream>>>(Xb, WcatT, Ycat, 4096, 10752, 2048);
  k_post<<<4096, 256, 0, stream>>>(Ycat, cosb, sinb, qw, kw);
  k_vt<<<dim3(64, 8, 8), tb, 0, stream>>>(Ycat, VT);
  k_attn<<<dim3(32, 16, 2), 256, 0, stream>>>(Ycat, VT, AO);
  k_gemm<1><<<dim3(16, 32), 256, 0, stream>>>(AO, WoT, d_out, 4096, 2048, 4096);
}

// Round 2
// 720.400 us; speedup vs baseline: 1.1651x; 1.1651x over previous
//
#include <hip/hip_runtime.h>

#define S_LEN 2048
#define NB    2
#define NH    16
#define NKV   4
#define HDIM  256
#define LW    10752   // Ycat row width: 8192 (q|gate) + 1024 (k) + 1024 (v) + 512 (r)

using bf16x8 = __attribute__((ext_vector_type(8))) short;
using s16x4  = __attribute__((ext_vector_type(4))) short;
using f32x4  = __attribute__((ext_vector_type(4))) float;

__device__ __forceinline__ float bf2f(short u){
  union { float f; unsigned u; } x; x.u = ((unsigned)(unsigned short)u) << 16; return x.f;
}
__device__ __forceinline__ short f2bf(float f){
  unsigned i = __builtin_bit_cast(unsigned, f);
  unsigned r = (i + 0x7fffu + ((i >> 16) & 1u)) >> 16;
  return (short)r;
}
__device__ __forceinline__ float sigm(float x){ return 1.0f / (1.0f + __expf(-x)); }

__device__ __forceinline__ void gload16(const short* g, short* lds){
  __builtin_amdgcn_global_load_lds((const __attribute__((address_space(1))) void*)g,
                                   (__attribute__((address_space(3))) void*)lds,
                                   16, 0, 0);
}

// ---------------- f32 -> bf16 elementwise ----------------
__global__ void k_cvt(const float* __restrict__ in, short* __restrict__ out, int n4){
  int i = blockIdx.x * blockDim.x + threadIdx.x;
  if (i >= n4) return;
  float4 v = ((const float4*)in)[i];
  s16x4 o;
  o[0] = f2bf(v.x); o[1] = f2bf(v.y); o[2] = f2bf(v.z); o[3] = f2bf(v.w);
  ((s16x4*)out)[i] = o;
}

// ---------------- f32 (R,C) -> bf16 (C,R) transpose+convert ----------------
__global__ void k_tcvt(const float* __restrict__ in, short* __restrict__ out, int R, int C){
  __shared__ float tile[32][33];
  int c0 = blockIdx.x * 32, r0 = blockIdx.y * 32;
  int tx = threadIdx.x, ty = threadIdx.y;   // (32, 8)
  #pragma unroll
  for (int i = ty; i < 32; i += 8)
    tile[i][tx] = in[(size_t)(r0 + i) * C + c0 + tx];
  __syncthreads();
  #pragma unroll
  for (int i = ty; i < 32; i += 8)
    out[(size_t)(c0 + i) * R + r0 + tx] = f2bf(tile[tx][i]);
}

// ---------------- bf16 V-slice transpose: Ycat v -> VT[b,hk,d,s] ----------------
__global__ void k_vt(const short* __restrict__ Ycat, short* __restrict__ VT){
  __shared__ short tile[32][33];
  int b = blockIdx.z >> 2, hk = blockIdx.z & 3;
  int s0 = blockIdx.x * 32, d0 = blockIdx.y * 32;
  int tx = threadIdx.x, ty = threadIdx.y;   // (32, 8)
  #pragma unroll
  for (int i = ty; i < 32; i += 8)
    tile[i][tx] = Ycat[(size_t)(b * S_LEN + s0 + i) * LW + 9216 + hk * 256 + d0 + tx];
  __syncthreads();
  #pragma unroll
  for (int i = ty; i < 32; i += 8)
    VT[(size_t)((b * NKV + hk) * HDIM + d0 + i) * S_LEN + s0 + tx] = tile[tx][i];
}

// ---------------- bf16 GEMM, BT form (m97 structure) ----------------
template<int OUTF32>
__global__ __launch_bounds__(256) void k_gemm(const short* __restrict__ A,
                                              const short* __restrict__ BT,
                                              void* __restrict__ C,
                                              int M, int N, int K)
{
  __shared__ __align__(16) short As[128 * 32];
  __shared__ __align__(16) short Bs[128 * 32];
  const int t = threadIdx.x, lane = t & 63, w = t >> 6;
  const int wr = w >> 1, wc = w & 1;
  const int m0 = blockIdx.y * 128, n0 = blockIdx.x * 128;
  f32x4 acc[4][4] = {};
  for (int k0 = 0; k0 < K; k0 += 32) {
    #pragma unroll
    for (int c = 0; c < 2; ++c) {
      gload16(A  + (size_t)(m0 + c*64 + w*16 + (lane >> 2)) * K + k0 + (lane & 3) * 8,
              As + c*2048 + w*512);
      gload16(BT + (size_t)(n0 + c*64 + w*16 + (lane >> 2)) * K + k0 + (lane & 3) * 8,
              Bs + c*2048 + w*512);
    }
    __syncthreads();
    bf16x8 af[4], bfr[4];
    #pragma unroll
    for (int i = 0; i < 4; ++i) {
      af[i]  = *(const bf16x8*)&As[(wr*64 + i*16 + (lane & 15)) * 32 + (lane >> 4) * 8];
      bfr[i] = *(const bf16x8*)&Bs[(wc*64 + i*16 + (lane & 15)) * 32 + (lane >> 4) * 8];
    }
    #pragma unroll
    for (int i = 0; i < 4; ++i)
      #pragma unroll
      for (int j = 0; j < 4; ++j)
        acc[i][j] = __builtin_amdgcn_mfma_f32_16x16x32_bf16(af[i], bfr[j], acc[i][j], 0, 0, 0);
    __syncthreads();
  }
  #pragma unroll
  for (int i = 0; i < 4; ++i)
    #pragma unroll
    for (int r = 0; r < 4; ++r) {
      int row = m0 + wr*64 + i*16 + (lane >> 4) * 4 + r;
      #pragma unroll
      for (int j = 0; j < 4; ++j) {
        int col = n0 + wc*64 + j*16 + (lane & 15);
        float v = acc[i][j][r];
        if (OUTF32) ((float*)C)[(size_t)row * N + col] = v;
        else        ((short*)C)[(size_t)row * N + col] = f2bf(v);
      }
    }
}

// ---------------- per-token: RMSNorm(q,k), gates, partial RoPE, in place ----------------
__global__ __launch_bounds__(256) void k_post(short* __restrict__ Ycat,
    const float* __restrict__ cosb, const float* __restrict__ sinb,
    const float* __restrict__ qw, const float* __restrict__ kw)
{
  const int tok = blockIdx.x;                 // b*S + s
  const int lane = threadIdx.x & 63, w = threadIdx.x >> 6;
  const size_t rowb = (size_t)tok * LW;
  const int d0 = lane * 4;

  float gq[4], gv[4];
  {
    s16x4 a  = *(const s16x4*)&Ycat[rowb + 10240 + d0];
    s16x4 bq = *(const s16x4*)&Ycat[rowb + 10240 + 256 + d0];
    #pragma unroll
    for (int j = 0; j < 4; ++j){ gq[j] = sigm(bf2f(a[j])); gv[j] = sigm(bf2f(bq[j])); }
  }
  float c4[4] = {0,0,0,0}, s4[4] = {0,0,0,0};
  if (lane < 16) {
    float4 c = *(const float4*)&cosb[(size_t)tok * 64 + d0];
    float4 s = *(const float4*)&sinb[(size_t)tok * 64 + d0];
    c4[0]=c.x; c4[1]=c.y; c4[2]=c.z; c4[3]=c.w;
    s4[0]=s.x; s4[1]=s.y; s4[2]=s.z; s4[3]=s.w;
  }
  float4 qv4 = *(const float4*)&qw[d0];
  float4 kv4 = *(const float4*)&kw[d0];
  float qwa[4] = {qv4.x, qv4.y, qv4.z, qv4.w};
  float kwa[4] = {kv4.x, kv4.y, kv4.z, kv4.w};

  #pragma unroll
  for (int hi = 0; hi < 4; ++hi) {
    const int hh = w * 4 + hi;
    const size_t off = rowb + hh * 512 + d0;
    s16x4 v = *(const s16x4*)&Ycat[off];
    float x[4];
    #pragma unroll
    for (int j = 0; j < 4; ++j) x[j] = bf2f(v[j]);
    float ss = x[0]*x[0] + x[1]*x[1] + x[2]*x[2] + x[3]*x[3];
    #pragma unroll
    for (int o2 = 1; o2 < 64; o2 <<= 1) ss += __shfl_xor(ss, o2);
    float rr = rsqrtf(ss * (1.0f/256.0f) + 1e-6f);
    #pragma unroll
    for (int j = 0; j < 4; ++j) x[j] = x[j] * rr * (1.0f + qwa[j]) * gq[j];
    float p[4];
    #pragma unroll
    for (int j = 0; j < 4; ++j) p[j] = __shfl_xor(x[j], 8);
    if (lane < 8)       { for (int j = 0; j < 4; ++j) x[j] = x[j]*c4[j] - p[j]*s4[j]; }
    else if (lane < 16) { for (int j = 0; j < 4; ++j) x[j] = x[j]*c4[j] + p[j]*s4[j]; }
    s16x4 o;
    #pragma unroll
    for (int j = 0; j < 4; ++j) o[j] = f2bf(x[j]);
    *(s16x4*)&Ycat[off] = o;
  }
  {
    const size_t off = rowb + 8192 + w * 256 + d0;
    s16x4 v = *(const s16x4*)&Ycat[off];
    float x[4];
    #pragma unroll
    for (int j = 0; j < 4; ++j) x[j] = bf2f(v[j]);
    float ss = x[0]*x[0] + x[1]*x[1] + x[2]*x[2] + x[3]*x[3];
    #pragma unroll
    for (int o2 = 1; o2 < 64; o2 <<= 1) ss += __shfl_xor(ss, o2);
    float rr = rsqrtf(ss * (1.0f/256.0f) + 1e-6f);
    #pragma unroll
    for (int j = 0; j < 4; ++j) x[j] = x[j] * rr * (1.0f + kwa[j]) * gq[j];
    float p[4];
    #pragma unroll
    for (int j = 0; j < 4; ++j) p[j] = __shfl_xor(x[j], 8);
    if (lane < 8)       { for (int j = 0; j < 4; ++j) x[j] = x[j]*c4[j] - p[j]*s4[j]; }
    else if (lane < 16) { for (int j = 0; j < 4; ++j) x[j] = x[j]*c4[j] + p[j]*s4[j]; }
    s16x4 o;
    #pragma unroll
    for (int j = 0; j < 4; ++j) o[j] = f2bf(x[j]);
    *(s16x4*)&Ycat[off] = o;
  }
  {
    const size_t off = rowb + 9216 + w * 256 + d0;
    s16x4 v = *(const s16x4*)&Ycat[off];
    s16x4 o;
    #pragma unroll
    for (int j = 0; j < 4; ++j) o[j] = f2bf(bf2f(v[j]) * gv[j]);
    *(s16x4*)&Ycat[off] = o;
  }
}

// ---------------- flash attention v2: QBLK=64, KVBLK=64, 4 waves ----------------
// 1-D grid of 1024: id = widx*8 + xcd; xcd = (b,hk) -> K/V L2 locality per XCD.
// widx: head-in-group * 32 + reversed q-block (largest first for load balance).
// LDS: K[64][256] + VT[256][64] + P[64][64], all XOR-swizzled (byte ^= (row&7)<<4),
// staged via global_load_lds w=16 with pre-swizzled global source (m173 pattern).
__global__ __launch_bounds__(256) void k_attn(const short* __restrict__ Ycat,
                                              const short* __restrict__ VT,
                                              short* __restrict__ AO)
{
  __shared__ __align__(16) short Ks[64 * 256];
  __shared__ __align__(16) short Vs[256 * 64];
  __shared__ __align__(16) short Ps[64 * 64];
  __shared__ float redLds[64];

  const int t = threadIdx.x, lane = t & 63, w = t >> 6;
  const int id = blockIdx.x;
  const int xcd = id & 7, widx = id >> 3;
  const int b = xcd >> 2, hk = xcd & 3;
  const int h = hk * 4 + (widx & 3);
  const int q0 = (31 - (widx >> 2)) * 64;

  // Q fragments: wave w owns q-rows w*16..w*16+15 (for QK^T)
  bf16x8 qf[8];
  {
    const size_t qb = ((size_t)(b * S_LEN) + q0 + w*16 + (lane & 15)) * LW
                    + h * 512 + ((lane >> 4) * 8);
    #pragma unroll
    for (int kk = 0; kk < 8; ++kk)
      qf[kk] = *(const bf16x8*)&Ycat[qb + kk * 32];
  }

  // staging address precompute (swizzle term is round-invariant: row&7 fixed)
  const int kRowL = w*2 + (lane >> 5);                     // + r*8 per round
  const int kColS = ((((lane & 31) * 16) ^ ((kRowL & 7) << 4)) >> 1);
  const int vRowL = w*8 + (lane >> 3);                     // + r*32 per round
  const int vColS = ((((lane & 7) * 16) ^ ((vRowL & 7) << 4)) >> 1);
  short* ldsK = Ks + t * 8;   // + r*2048 per round
  short* ldsV = Vs + t * 8;
  const short* kBase = Ycat + ((size_t)(b * S_LEN) + kRowL) * LW + 8192 + hk * 256 + kColS;
  const short* vBase = VT + ((size_t)((b * NKV + hk) * HDIM + vRowL)) * S_LEN + vColS;

  f32x4 oacc[4][4] = {};
  float m_r[4], l_r[4];
  #pragma unroll
  for (int r = 0; r < 4; ++r){ m_r[r] = -1e30f; l_r[r] = 0.0f; }

  for (int j0 = 0; j0 <= q0; j0 += 64) {
    // ---- stage K (64x256) and V^T (256x64), swizzled source -> linear LDS
    #pragma unroll
    for (int r = 0; r < 8; ++r) {
      gload16(kBase + (size_t)(j0 + r*8) * LW, ldsK + r * 2048);
      gload16(vBase + j0 + (size_t)(r*32) * S_LEN, ldsV + r * 2048);
    }
    __syncthreads();   // drains vmcnt(0)

    // ---- QK^T: wave's 16 q-rows x 64 keys, K=256
    f32x4 sa[4] = {};
    #pragma unroll
    for (int kk = 0; kk < 8; ++kk) {
      #pragma unroll
      for (int c = 0; c < 4; ++c) {
        const int row = c*16 + (lane & 15);
        const int colb = (kk*64 + (lane >> 4) * 16) ^ ((row & 7) << 4);
        bf16x8 kf = *(const bf16x8*)((const char*)Ks + row * 512 + colb);
        sa[c] = __builtin_amdgcn_mfma_f32_16x16x32_bf16(qf[kk], kf, sa[c], 0, 0, 0);
      }
    }

    // ---- online softmax (row = (lane>>4)*4+r within wave; 16-lane reduce)
    const bool diag = (j0 + 64 > q0);
    #pragma unroll
    for (int r = 0; r < 4; ++r) {
      const int qrow = w*16 + (lane >> 4) * 4 + r;
      float s[4];
      #pragma unroll
      for (int c = 0; c < 4; ++c) s[c] = sa[c][r] * 0.0625f;
      if (diag) {
        const int qg = q0 + qrow;
        #pragma unroll
        for (int c = 0; c < 4; ++c)
          if (j0 + c*16 + (lane & 15) > qg) s[c] = -1e9f;
      }
      float mx = fmaxf(fmaxf(s[0], s[1]), fmaxf(s[2], s[3]));
      #pragma unroll
      for (int off = 1; off < 16; off <<= 1) mx = fmaxf(mx, __shfl_xor(mx, off));
      const float mnew  = fmaxf(m_r[r], mx);
      const float alpha = __expf(m_r[r] - mnew);
      float p[4], rs = 0.0f;
      #pragma unroll
      for (int c = 0; c < 4; ++c) { p[c] = __expf(s[c] - mnew); rs += p[c]; }
      #pragma unroll
      for (int off = 1; off < 16; off <<= 1) rs += __shfl_xor(rs, off);
      l_r[r] = alpha * l_r[r] + rs;
      m_r[r] = mnew;
      if ((lane & 15) == 0) redLds[qrow] = alpha;
      #pragma unroll
      for (int c = 0; c < 4; ++c) {
        const int key = c*16 + (lane & 15);
        *(short*)((char*)Ps + qrow * 128 + ((key * 2) ^ ((qrow & 7) << 4))) = f2bf(p[c]);
      }
    }
    __syncthreads();

    // ---- rescale O, then PV (wave owns d-quarter w*64..w*64+63, all 64 rows)
    #pragma unroll
    for (int i = 0; i < 4; ++i)
      #pragma unroll
      for (int r = 0; r < 4; ++r) {
        const float a = redLds[i*16 + (lane >> 4) * 4 + r];
        #pragma unroll
        for (int j = 0; j < 4; ++j) oacc[i][j][r] *= a;
      }
    #pragma unroll
    for (int ks = 0; ks < 2; ++ks) {
      bf16x8 pa[4];
      #pragma unroll
      for (int i = 0; i < 4; ++i) {
        const int row = i*16 + (lane & 15);
        const int colb = (ks*64 + (lane >> 4) * 16) ^ ((row & 7) << 4);
        pa[i] = *(const bf16x8*)((const char*)Ps + row * 128 + colb);
      }
      #pragma unroll
      for (int j = 0; j < 4; ++j) {
        const int vrow = w*64 + j*16 + (lane & 15);
        const int colb = (ks*64 + (lane >> 4) * 16) ^ ((vrow & 7) << 4);
        bf16x8 vf = *(const bf16x8*)((const char*)Vs + vrow * 128 + colb);
        #pragma unroll
        for (int i = 0; i < 4; ++i)
          oacc[i][j] = __builtin_amdgcn_mfma_f32_16x16x32_bf16(pa[i], vf, oacc[i][j], 0, 0, 0);
      }
    }
    __syncthreads();
  }

  // publish denominators
  if ((lane & 15) == 0) {
    #pragma unroll
    for (int r = 0; r < 4; ++r)
      redLds[w*16 + (lane >> 4) * 4 + r] = l_r[r];
  }
  __syncthreads();

  // epilogue: O/l * sigmoid(gate) -> AO[b,s, h*256+d]
  #pragma unroll
  for (int i = 0; i < 4; ++i)
    #pragma unroll
    for (int r = 0; r < 4; ++r) {
      const int row = i*16 + (lane >> 4) * 4 + r;
      const float linv = 1.0f / redLds[row];
      const int qg = q0 + row;
      const size_t gb = ((size_t)(b * S_LEN) + qg) * LW + h * 512 + 256;
      const size_t ob = ((size_t)(b * S_LEN) + qg) * 4096 + h * 256;
      #pragma unroll
      for (int j = 0; j < 4; ++j) {
        const int d = w*64 + j*16 + (lane & 15);
        const float g = sigm(bf2f(Ycat[gb + d]));
        AO[ob + d] = f2bf(oacc[i][j][r] * linv * g);
      }
    }
}

extern "C" void kernel_launch(void* const* d_in, const int* in_sizes, int n_in,
                              void* d_out, int out_size, void* d_ws, size_t ws_size,
                              hipStream_t stream) {
  const float* X    = (const float*)d_in[0];
  const float* cosb = (const float*)d_in[1];
  const float* sinb = (const float*)d_in[2];
  const float* Wq   = (const float*)d_in[4];
  const float* Wk   = (const float*)d_in[5];
  const float* Wv   = (const float*)d_in[6];
  const float* Wo   = (const float*)d_in[7];
  const float* qw   = (const float*)d_in[8];
  const float* kw   = (const float*)d_in[9];
  const float* Wr   = (const float*)d_in[10];

  short* Xb    = (short*)d_ws;                       //  8,388,608
  short* WcatT = Xb    +  8388608;                   // 22,020,096
  short* AO    = WcatT;                              // alias (dead after GEMM0)
  short* WoT   = WcatT + 22020096;                   //  8,388,608
  short* Ycat  = WoT   +  8388608;                   // 44,040,192
  short* VT    = Ycat  + 44040192;                   //  4,194,304

  dim3 tb(32, 8);
  k_cvt<<<8192, 256, 0, stream>>>(X, Xb, 2097152);
  k_tcvt<<<dim3(256, 64), tb, 0, stream>>>(Wq, WcatT,                      2048, 8192);
  k_tcvt<<<dim3( 32, 64), tb, 0, stream>>>(Wk, WcatT + (size_t)8192*2048,  2048, 1024);
  k_tcvt<<<dim3( 32, 64), tb, 0, stream>>>(Wv, WcatT + (size_t)9216*2048,  2048, 1024);
  k_tcvt<<<dim3( 16, 64), tb, 0, stream>>>(Wr, WcatT + (size_t)10240*2048, 2048,  512);
  k_tcvt<<<dim3( 64,128), tb, 0, stream>>>(Wo, WoT,                        4096, 2048);

  k_gemm<0><<<dim3(84, 32), 256, 0, stream>>>(Xb, WcatT, Ycat, 4096, 10752, 2048);
  k_post<<<4096, 256, 0, stream>>>(Ycat, cosb, sinb, qw, kw);
  k_vt<<<dim3(64, 8, 8), tb, 0, stream>>>(Ycat, VT);
  k_attn<<<1024, 256, 0, stream>>>(Ycat, VT, AO);
  k_gemm<1><<<dim3(16, 32), 256, 0, stream>>>(AO, WoT, d_out, 4096, 2048, 4096);
}

// Round 3
// 666.939 us; speedup vs baseline: 1.2585x; 1.0802x over previous
//
#include <hip/hip_runtime.h>

#define S_LEN 2048
#define NB    2
#define NH    16
#define NKV   4
#define HDIM  256
#define LW    10752   // Ycat row width: 8192 (q|gate) + 1024 (k) + 1024 (v) + 512 (r)

using bf16x8 = __attribute__((ext_vector_type(8))) short;
using s16x4  = __attribute__((ext_vector_type(4))) short;
using f32x4  = __attribute__((ext_vector_type(4))) float;

__device__ __forceinline__ float bf2f(short u){
  union { float f; unsigned u; } x; x.u = ((unsigned)(unsigned short)u) << 16; return x.f;
}
__device__ __forceinline__ short f2bf(float f){
  unsigned i = __builtin_bit_cast(unsigned, f);
  unsigned r = (i + 0x7fffu + ((i >> 16) & 1u)) >> 16;
  return (short)r;
}
__device__ __forceinline__ float sigm(float x){ return 1.0f / (1.0f + __expf(-x)); }

__device__ __forceinline__ void gload16(const short* g, short* lds){
  __builtin_amdgcn_global_load_lds((const __attribute__((address_space(1))) void*)g,
                                   (__attribute__((address_space(3))) void*)lds,
                                   16, 0, 0);
}

// ---------------- f32 -> bf16 elementwise ----------------
__global__ void k_cvt(const float* __restrict__ in, short* __restrict__ out, int n4){
  int i = blockIdx.x * blockDim.x + threadIdx.x;
  if (i >= n4) return;
  float4 v = ((const float4*)in)[i];
  s16x4 o;
  o[0] = f2bf(v.x); o[1] = f2bf(v.y); o[2] = f2bf(v.z); o[3] = f2bf(v.w);
  ((s16x4*)out)[i] = o;
}

// ---------------- f32 (R,C) -> bf16 (C,R) transpose+convert ----------------
__global__ void k_tcvt(const float* __restrict__ in, short* __restrict__ out, int R, int C){
  __shared__ float tile[32][33];
  int c0 = blockIdx.x * 32, r0 = blockIdx.y * 32;
  int tx = threadIdx.x, ty = threadIdx.y;   // (32, 8)
  #pragma unroll
  for (int i = ty; i < 32; i += 8)
    tile[i][tx] = in[(size_t)(r0 + i) * C + c0 + tx];
  __syncthreads();
  #pragma unroll
  for (int i = ty; i < 32; i += 8)
    out[(size_t)(c0 + i) * R + r0 + tx] = f2bf(tile[tx][i]);
}

// ---------------- bf16 V-slice transpose: Ycat v -> VT[b,hk,d,s] ----------------
__global__ void k_vt(const short* __restrict__ Ycat, short* __restrict__ VT){
  __shared__ short tile[32][33];
  int b = blockIdx.z >> 2, hk = blockIdx.z & 3;
  int s0 = blockIdx.x * 32, d0 = blockIdx.y * 32;
  int tx = threadIdx.x, ty = threadIdx.y;   // (32, 8)
  #pragma unroll
  for (int i = ty; i < 32; i += 8)
    tile[i][tx] = Ycat[(size_t)(b * S_LEN + s0 + i) * LW + 9216 + hk * 256 + d0 + tx];
  __syncthreads();
  #pragma unroll
  for (int i = ty; i < 32; i += 8)
    VT[(size_t)((b * NKV + hk) * HDIM + d0 + i) * S_LEN + s0 + tx] = tile[tx][i];
}

// ================= 256x256 8-phase bf16 GEMM (T1+T2+T3/T4+T5) =================
// C[M,N] = A[M,K] * BT[N,K]^T ; BM=BN=256, BK=64, 512 thr = 8 waves (2M x 4N).
// LDS [2buf][2kstep][256 rows][32k] per operand = 128 KiB total.
// Per phase: 4-8 ds_read_b128 + 1 half-tile (2x gload_lds w=16) -> barrier ->
// lgkmcnt(0) -> setprio(1) 16 MFMA setprio(0) -> barrier. vmcnt(4) at P3/P7 only.
// Read swizzle: slot = (lane>>4) ^ (row&3); staging pre-swizzles the global src.
#define MFMA_(a, b, c) __builtin_amdgcn_mfma_f32_16x16x32_bf16(a, b, c, 0, 0, 0)
#define LDA_(buf, ks, mh, f) (*(const bf16x8*)&As[buf][ks][(wm*128 + (mh)*64 + (f)*16 + l15) * 32 + rdSlot])
#define LDB_(buf, ks, f)     (*(const bf16x8*)&Bs[buf][ks][(wn*64  + (f)*16 + l15) * 32 + rdSlot])
#define STAGE_A_(buf, ks, tile) { \
  gload16(aG0 + (size_t)(tile)*64 + (ks)*32, &As[buf][ks][w*512]); \
  gload16(aG1 + (size_t)(tile)*64 + (ks)*32, &As[buf][ks][4096 + w*512]); }
#define STAGE_B_(buf, ks, tile) { \
  gload16(bG0 + (size_t)(tile)*64 + (ks)*32, &Bs[buf][ks][w*512]); \
  gload16(bG1 + (size_t)(tile)*64 + (ks)*32, &Bs[buf][ks][4096 + w*512]); }
#define VM4 asm volatile("s_waitcnt vmcnt(4)" ::: "memory");
#define PH_(buf, ks, mh, LB, ...) { \
  bf16x8 a0 = LDA_(buf,ks,mh,0), a1 = LDA_(buf,ks,mh,1), a2 = LDA_(buf,ks,mh,2), a3 = LDA_(buf,ks,mh,3); \
  if (LB) { b0 = LDB_(buf,ks,0); b1 = LDB_(buf,ks,1); b2 = LDB_(buf,ks,2); b3 = LDB_(buf,ks,3); } \
  __VA_ARGS__ \
  __builtin_amdgcn_s_barrier(); \
  asm volatile("s_waitcnt lgkmcnt(0)" ::: "memory"); \
  __builtin_amdgcn_s_setprio(1); \
  acc[(mh)*4+0][0] = MFMA_(a0, b0, acc[(mh)*4+0][0]); \
  acc[(mh)*4+0][1] = MFMA_(a0, b1, acc[(mh)*4+0][1]); \
  acc[(mh)*4+0][2] = MFMA_(a0, b2, acc[(mh)*4+0][2]); \
  acc[(mh)*4+0][3] = MFMA_(a0, b3, acc[(mh)*4+0][3]); \
  acc[(mh)*4+1][0] = MFMA_(a1, b0, acc[(mh)*4+1][0]); \
  acc[(mh)*4+1][1] = MFMA_(a1, b1, acc[(mh)*4+1][1]); \
  acc[(mh)*4+1][2] = MFMA_(a1, b2, acc[(mh)*4+1][2]); \
  acc[(mh)*4+1][3] = MFMA_(a1, b3, acc[(mh)*4+1][3]); \
  acc[(mh)*4+2][0] = MFMA_(a2, b0, acc[(mh)*4+2][0]); \
  acc[(mh)*4+2][1] = MFMA_(a2, b1, acc[(mh)*4+2][1]); \
  acc[(mh)*4+2][2] = MFMA_(a2, b2, acc[(mh)*4+2][2]); \
  acc[(mh)*4+2][3] = MFMA_(a2, b3, acc[(mh)*4+2][3]); \
  acc[(mh)*4+3][0] = MFMA_(a3, b0, acc[(mh)*4+3][0]); \
  acc[(mh)*4+3][1] = MFMA_(a3, b1, acc[(mh)*4+3][1]); \
  acc[(mh)*4+3][2] = MFMA_(a3, b2, acc[(mh)*4+3][2]); \
  acc[(mh)*4+3][3] = MFMA_(a3, b3, acc[(mh)*4+3][3]); \
  __builtin_amdgcn_s_setprio(0); \
  __builtin_amdgcn_s_barrier(); }

template<int OUTF32>
__global__ __launch_bounds__(512) void k_gemm2(const short* __restrict__ A,
                                               const short* __restrict__ BT,
                                               void* __restrict__ C,
                                               int M, int N, int K, int gx)
{
  __shared__ __align__(16) short As[2][2][8192];
  __shared__ __align__(16) short Bs[2][2][8192];
  const int t = threadIdx.x, lane = t & 63, w = t >> 6;
  const int l15 = lane & 15;
  const int wm = w >> 2, wn = w & 3;
  const int rdSlot = (((lane >> 4) ^ (lane & 3)) * 8);

  // XCD-aware bijective swizzle (nwg % 8 == 0 for both call sites)
  const int nwg = gridDim.x;
  const int swz = (blockIdx.x & 7) * (nwg >> 3) + (blockIdx.x >> 3);
  const int m0 = (swz / gx) * 256, n0 = (swz % gx) * 256;

  // staging constants: line l covers rows l*128..+127; source k pre-swizzled
  const int sRow = w * 16 + (lane >> 2);
  const int sSwz = ((lane & 3) ^ ((lane >> 2) & 3)) * 8;
  const short* aG0 = A  + (size_t)(m0 + sRow) * K + sSwz;
  const short* aG1 = A  + (size_t)(m0 + 128 + sRow) * K + sSwz;
  const short* bG0 = BT + (size_t)(n0 + sRow) * K + sSwz;
  const short* bG1 = BT + (size_t)(n0 + 128 + sRow) * K + sSwz;

  f32x4 acc[8][4] = {};
  bf16x8 b0 = {}, b1 = {}, b2 = {}, b3 = {};

  // prologue: tile0 all 4 halves + tile1 {A.k0, B.k0}
  STAGE_A_(0, 0, 0) STAGE_A_(0, 1, 0) STAGE_B_(0, 0, 0) STAGE_B_(0, 1, 0)
  STAGE_A_(1, 0, 1) STAGE_B_(1, 0, 1)
  asm volatile("s_waitcnt vmcnt(4)" ::: "memory");
  __builtin_amdgcn_s_barrier();

  const int nIt = K >> 7;   // pairs of 64-K tiles
  for (int i = 0; i < nIt; ++i) {
    const int c = 2 * i;
    const bool st = (i + 1 < nIt);
    PH_(0, 0, 0, 1, STAGE_A_(1, 1, c + 1))
    PH_(0, 0, 1, 0, STAGE_B_(1, 1, c + 1))
    PH_(0, 1, 0, 1, if (st) STAGE_A_(0, 0, c + 2))
    PH_(0, 1, 1, 0, if (st) STAGE_B_(0, 0, c + 2) VM4)
    PH_(1, 0, 0, 1, if (st) STAGE_A_(0, 1, c + 2))
    PH_(1, 0, 1, 0, if (st) STAGE_B_(0, 1, c + 2))
    PH_(1, 1, 0, 1, if (st) STAGE_A_(1, 0, c + 3))
    PH_(1, 1, 1, 0, if (st) STAGE_B_(1, 0, c + 3) VM4)
  }

  // epilogue
  #pragma unroll
  for (int ii = 0; ii < 8; ++ii)
    #pragma unroll
    for (int r = 0; r < 4; ++r) {
      const int row = m0 + wm * 128 + ii * 16 + (lane >> 4) * 4 + r;
      #pragma unroll
      for (int j = 0; j < 4; ++j) {
        const int col = n0 + wn * 64 + j * 16 + l15;
        const float v = acc[ii][j][r];
        if (OUTF32) ((float*)C)[(size_t)row * N + col] = v;
        else        ((short*)C)[(size_t)row * N + col] = f2bf(v);
      }
    }
}

// ---------------- per-token: RMSNorm(q,k), gates, partial RoPE, in place ----------------
__global__ __launch_bounds__(256) void k_post(short* __restrict__ Ycat,
    const float* __restrict__ cosb, const float* __restrict__ sinb,
    const float* __restrict__ qw, const float* __restrict__ kw)
{
  const int tok = blockIdx.x;                 // b*S + s
  const int lane = threadIdx.x & 63, w = threadIdx.x >> 6;
  const size_t rowb = (size_t)tok * LW;
  const int d0 = lane * 4;

  float gq[4], gv[4];
  {
    s16x4 a  = *(const s16x4*)&Ycat[rowb + 10240 + d0];
    s16x4 bq = *(const s16x4*)&Ycat[rowb + 10240 + 256 + d0];
    #pragma unroll
    for (int j = 0; j < 4; ++j){ gq[j] = sigm(bf2f(a[j])); gv[j] = sigm(bf2f(bq[j])); }
  }
  float c4[4] = {0,0,0,0}, s4[4] = {0,0,0,0};
  if (lane < 16) {
    float4 c = *(const float4*)&cosb[(size_t)tok * 64 + d0];
    float4 s = *(const float4*)&sinb[(size_t)tok * 64 + d0];
    c4[0]=c.x; c4[1]=c.y; c4[2]=c.z; c4[3]=c.w;
    s4[0]=s.x; s4[1]=s.y; s4[2]=s.z; s4[3]=s.w;
  }
  float4 qv4 = *(const float4*)&qw[d0];
  float4 kv4 = *(const float4*)&kw[d0];
  float qwa[4] = {qv4.x, qv4.y, qv4.z, qv4.w};
  float kwa[4] = {kv4.x, kv4.y, kv4.z, kv4.w};

  #pragma unroll
  for (int hi = 0; hi < 4; ++hi) {
    const int hh = w * 4 + hi;
    const size_t off = rowb + hh * 512 + d0;
    s16x4 v = *(const s16x4*)&Ycat[off];
    float x[4];
    #pragma unroll
    for (int j = 0; j < 4; ++j) x[j] = bf2f(v[j]);
    float ss = x[0]*x[0] + x[1]*x[1] + x[2]*x[2] + x[3]*x[3];
    #pragma unroll
    for (int o2 = 1; o2 < 64; o2 <<= 1) ss += __shfl_xor(ss, o2);
    float rr = rsqrtf(ss * (1.0f/256.0f) + 1e-6f);
    #pragma unroll
    for (int j = 0; j < 4; ++j) x[j] = x[j] * rr * (1.0f + qwa[j]) * gq[j];
    float p[4];
    #pragma unroll
    for (int j = 0; j < 4; ++j) p[j] = __shfl_xor(x[j], 8);
    if (lane < 8)       { for (int j = 0; j < 4; ++j) x[j] = x[j]*c4[j] - p[j]*s4[j]; }
    else if (lane < 16) { for (int j = 0; j < 4; ++j) x[j] = x[j]*c4[j] + p[j]*s4[j]; }
    s16x4 o;
    #pragma unroll
    for (int j = 0; j < 4; ++j) o[j] = f2bf(x[j]);
    *(s16x4*)&Ycat[off] = o;
  }
  {
    const size_t off = rowb + 8192 + w * 256 + d0;
    s16x4 v = *(const s16x4*)&Ycat[off];
    float x[4];
    #pragma unroll
    for (int j = 0; j < 4; ++j) x[j] = bf2f(v[j]);
    float ss = x[0]*x[0] + x[1]*x[1] + x[2]*x[2] + x[3]*x[3];
    #pragma unroll
    for (int o2 = 1; o2 < 64; o2 <<= 1) ss += __shfl_xor(ss, o2);
    float rr = rsqrtf(ss * (1.0f/256.0f) + 1e-6f);
    #pragma unroll
    for (int j = 0; j < 4; ++j) x[j] = x[j] * rr * (1.0f + kwa[j]) * gq[j];
    float p[4];
    #pragma unroll
    for (int j = 0; j < 4; ++j) p[j] = __shfl_xor(x[j], 8);
    if (lane < 8)       { for (int j = 0; j < 4; ++j) x[j] = x[j]*c4[j] - p[j]*s4[j]; }
    else if (lane < 16) { for (int j = 0; j < 4; ++j) x[j] = x[j]*c4[j] + p[j]*s4[j]; }
    s16x4 o;
    #pragma unroll
    for (int j = 0; j < 4; ++j) o[j] = f2bf(x[j]);
    *(s16x4*)&Ycat[off] = o;
  }
  {
    const size_t off = rowb + 9216 + w * 256 + d0;
    s16x4 v = *(const s16x4*)&Ycat[off];
    s16x4 o;
    #pragma unroll
    for (int j = 0; j < 4; ++j) o[j] = f2bf(bf2f(v[j]) * gv[j]);
    *(s16x4*)&Ycat[off] = o;
  }
}

// ---------------- flash attention: QBLK=64, KVBLK=64, 4 waves ----------------
__global__ __launch_bounds__(256) void k_attn(const short* __restrict__ Ycat,
                                              const short* __restrict__ VT,
                                              short* __restrict__ AO)
{
  __shared__ __align__(16) short Ks[64 * 256];
  __shared__ __align__(16) short Vs[256 * 64];
  __shared__ __align__(16) short Ps[64 * 64];
  __shared__ float redLds[64];

  const int t = threadIdx.x, lane = t & 63, w = t >> 6;
  const int id = blockIdx.x;
  const int xcd = id & 7, widx = id >> 3;
  const int b = xcd >> 2, hk = xcd & 3;
  const int h = hk * 4 + (widx & 3);
  const int q0 = (31 - (widx >> 2)) * 64;

  bf16x8 qf[8];
  {
    const size_t qb = ((size_t)(b * S_LEN) + q0 + w*16 + (lane & 15)) * LW
                    + h * 512 + ((lane >> 4) * 8);
    #pragma unroll
    for (int kk = 0; kk < 8; ++kk)
      qf[kk] = *(const bf16x8*)&Ycat[qb + kk * 32];
  }

  const int kRowL = w*2 + (lane >> 5);
  const int kColS = ((((lane & 31) * 16) ^ ((kRowL & 7) << 4)) >> 1);
  const int vRowL = w*8 + (lane >> 3);
  const int vColS = ((((lane & 7) * 16) ^ ((vRowL & 7) << 4)) >> 1);
  short* ldsK = Ks + t * 8;
  short* ldsV = Vs + t * 8;
  const short* kBase = Ycat + ((size_t)(b * S_LEN) + kRowL) * LW + 8192 + hk * 256 + kColS;
  const short* vBase = VT + ((size_t)((b * NKV + hk) * HDIM + vRowL)) * S_LEN + vColS;

  f32x4 oacc[4][4] = {};
  float m_r[4], l_r[4];
  #pragma unroll
  for (int r = 0; r < 4; ++r){ m_r[r] = -1e30f; l_r[r] = 0.0f; }

  for (int j0 = 0; j0 <= q0; j0 += 64) {
    #pragma unroll
    for (int r = 0; r < 8; ++r) {
      gload16(kBase + (size_t)(j0 + r*8) * LW, ldsK + r * 2048);
      gload16(vBase + j0 + (size_t)(r*32) * S_LEN, ldsV + r * 2048);
    }
    __syncthreads();

    f32x4 sa[4] = {};
    #pragma unroll
    for (int kk = 0; kk < 8; ++kk) {
      #pragma unroll
      for (int c = 0; c < 4; ++c) {
        const int row = c*16 + (lane & 15);
        const int colb = (kk*64 + (lane >> 4) * 16) ^ ((row & 7) << 4);
        bf16x8 kf = *(const bf16x8*)((const char*)Ks + row * 512 + colb);
        sa[c] = __builtin_amdgcn_mfma_f32_16x16x32_bf16(qf[kk], kf, sa[c], 0, 0, 0);
      }
    }

    const bool diag = (j0 + 64 > q0);
    #pragma unroll
    for (int r = 0; r < 4; ++r) {
      const int qrow = w*16 + (lane >> 4) * 4 + r;
      float s[4];
      #pragma unroll
      for (int c = 0; c < 4; ++c) s[c] = sa[c][r] * 0.0625f;
      if (diag) {
        const int qg = q0 + qrow;
        #pragma unroll
        for (int c = 0; c < 4; ++c)
          if (j0 + c*16 + (lane & 15) > qg) s[c] = -1e9f;
      }
      float mx = fmaxf(fmaxf(s[0], s[1]), fmaxf(s[2], s[3]));
      #pragma unroll
      for (int off = 1; off < 16; off <<= 1) mx = fmaxf(mx, __shfl_xor(mx, off));
      const float mnew  = fmaxf(m_r[r], mx);
      const float alpha = __expf(m_r[r] - mnew);
      float p[4], rs = 0.0f;
      #pragma unroll
      for (int c = 0; c < 4; ++c) { p[c] = __expf(s[c] - mnew); rs += p[c]; }
      #pragma unroll
      for (int off = 1; off < 16; off <<= 1) rs += __shfl_xor(rs, off);
      l_r[r] = alpha * l_r[r] + rs;
      m_r[r] = mnew;
      if ((lane & 15) == 0) redLds[qrow] = alpha;
      #pragma unroll
      for (int c = 0; c < 4; ++c) {
        const int key = c*16 + (lane & 15);
        *(short*)((char*)Ps + qrow * 128 + ((key * 2) ^ ((qrow & 7) << 4))) = f2bf(p[c]);
      }
    }
    __syncthreads();

    #pragma unroll
    for (int i = 0; i < 4; ++i)
      #pragma unroll
      for (int r = 0; r < 4; ++r) {
        const float a = redLds[i*16 + (lane >> 4) * 4 + r];
        #pragma unroll
        for (int j = 0; j < 4; ++j) oacc[i][j][r] *= a;
      }
    #pragma unroll
    for (int ks = 0; ks < 2; ++ks) {
      bf16x8 pa[4];
      #pragma unroll
      for (int i = 0; i < 4; ++i) {
        const int row = i*16 + (lane & 15);
        const int colb = (ks*64 + (lane >> 4) * 16) ^ ((row & 7) << 4);
        pa[i] = *(const bf16x8*)((const char*)Ps + row * 128 + colb);
      }
      #pragma unroll
      for (int j = 0; j < 4; ++j) {
        const int vrow = w*64 + j*16 + (lane & 15);
        const int colb = (ks*64 + (lane >> 4) * 16) ^ ((vrow & 7) << 4);
        bf16x8 vf = *(const bf16x8*)((const char*)Vs + vrow * 128 + colb);
        #pragma unroll
        for (int i = 0; i < 4; ++i)
          oacc[i][j] = __builtin_amdgcn_mfma_f32_16x16x32_bf16(pa[i], vf, oacc[i][j], 0, 0, 0);
      }
    }
    __syncthreads();
  }

  if ((lane & 15) == 0) {
    #pragma unroll
    for (int r = 0; r < 4; ++r)
      redLds[w*16 + (lane >> 4) * 4 + r] = l_r[r];
  }
  __syncthreads();

  #pragma unroll
  for (int i = 0; i < 4; ++i)
    #pragma unroll
    for (int r = 0; r < 4; ++r) {
      const int row = i*16 + (lane >> 4) * 4 + r;
      const float linv = 1.0f / redLds[row];
      const int qg = q0 + row;
      const size_t gb = ((size_t)(b * S_LEN) + qg) * LW + h * 512 + 256;
      const size_t ob = ((size_t)(b * S_LEN) + qg) * 4096 + h * 256;
      #pragma unroll
      for (int j = 0; j < 4; ++j) {
        const int d = w*64 + j*16 + (lane & 15);
        const float g = sigm(bf2f(Ycat[gb + d]));
        AO[ob + d] = f2bf(oacc[i][j][r] * linv * g);
      }
    }
}

extern "C" void kernel_launch(void* const* d_in, const int* in_sizes, int n_in,
                              void* d_out, int out_size, void* d_ws, size_t ws_size,
                              hipStream_t stream) {
  const float* X    = (const float*)d_in[0];
  const float* cosb = (const float*)d_in[1];
  const float* sinb = (const float*)d_in[2];
  const float* Wq   = (const float*)d_in[4];
  const float* Wk   = (const float*)d_in[5];
  const float* Wv   = (const float*)d_in[6];
  const float* Wo   = (const float*)d_in[7];
  const float* qw   = (const float*)d_in[8];
  const float* kw   = (const float*)d_in[9];
  const float* Wr   = (const float*)d_in[10];

  short* Xb    = (short*)d_ws;                       //  8,388,608
  short* WcatT = Xb    +  8388608;                   // 22,020,096
  short* AO    = WcatT;                              // alias (dead after GEMM0)
  short* WoT   = WcatT + 22020096;                   //  8,388,608
  short* Ycat  = WoT   +  8388608;                   // 44,040,192
  short* VT    = Ycat  + 44040192;                   //  4,194,304

  dim3 tb(32, 8);
  k_cvt<<<8192, 256, 0, stream>>>(X, Xb, 2097152);
  k_tcvt<<<dim3(256, 64), tb, 0, stream>>>(Wq, WcatT,                      2048, 8192);
  k_tcvt<<<dim3( 32, 64), tb, 0, stream>>>(Wk, WcatT + (size_t)8192*2048,  2048, 1024);
  k_tcvt<<<dim3( 32, 64), tb, 0, stream>>>(Wv, WcatT + (size_t)9216*2048,  2048, 1024);
  k_tcvt<<<dim3( 16, 64), tb, 0, stream>>>(Wr, WcatT + (size_t)10240*2048, 2048,  512);
  k_tcvt<<<dim3( 64,128), tb, 0, stream>>>(Wo, WoT,                        4096, 2048);

  k_gemm2<0><<<672, 512, 0, stream>>>(Xb, WcatT, Ycat, 4096, 10752, 2048, 42);
  k_post<<<4096, 256, 0, stream>>>(Ycat, cosb, sinb, qw, kw);
  k_vt<<<dim3(64, 8, 8), tb, 0, stream>>>(Ycat, VT);
  k_attn<<<1024, 256, 0, stream>>>(Ycat, VT, AO);
  k_gemm2<1><<<128, 512, 0, stream>>>(AO, WoT, d_out, 4096, 2048, 4096, 8);
}

// Round 4
// 551.812 us; speedup vs baseline: 1.5211x; 1.2086x over previous
//
#include <hip/hip_runtime.h>

#define S_LEN 2048
#define NB    2
#define NH    16
#define NKV   4
#define HDIM  256
#define LW    10752   // Ycat row width: 8192 (q|gate) + 1024 (k) + 1024 (v) + 512 (r)

using bf16x8 = __attribute__((ext_vector_type(8))) short;
using s16x4  = __attribute__((ext_vector_type(4))) short;
using f32x4  = __attribute__((ext_vector_type(4))) float;

__device__ __forceinline__ float bf2f(short u){
  union { float f; unsigned u; } x; x.u = ((unsigned)(unsigned short)u) << 16; return x.f;
}
__device__ __forceinline__ short f2bf(float f){
  unsigned i = __builtin_bit_cast(unsigned, f);
  unsigned r = (i + 0x7fffu + ((i >> 16) & 1u)) >> 16;
  return (short)r;
}
__device__ __forceinline__ float sigm(float x){ return 1.0f / (1.0f + __expf(-x)); }

__device__ __forceinline__ void gload16(const short* g, short* lds){
  __builtin_amdgcn_global_load_lds((const __attribute__((address_space(1))) void*)g,
                                   (__attribute__((address_space(3))) void*)lds,
                                   16, 0, 0);
}

// ---------------- f32 -> bf16 elementwise ----------------
__global__ void k_cvt(const float* __restrict__ in, short* __restrict__ out, int n4){
  int i = blockIdx.x * blockDim.x + threadIdx.x;
  if (i >= n4) return;
  float4 v = ((const float4*)in)[i];
  s16x4 o;
  o[0] = f2bf(v.x); o[1] = f2bf(v.y); o[2] = f2bf(v.z); o[3] = f2bf(v.w);
  ((s16x4*)out)[i] = o;
}

// ---------------- f32 (R,C) -> bf16 (C,R) transpose+convert ----------------
__global__ void k_tcvt(const float* __restrict__ in, short* __restrict__ out, int R, int C){
  __shared__ float tile[32][33];
  int c0 = blockIdx.x * 32, r0 = blockIdx.y * 32;
  int tx = threadIdx.x, ty = threadIdx.y;   // (32, 8)
  #pragma unroll
  for (int i = ty; i < 32; i += 8)
    tile[i][tx] = in[(size_t)(r0 + i) * C + c0 + tx];
  __syncthreads();
  #pragma unroll
  for (int i = ty; i < 32; i += 8)
    out[(size_t)(c0 + i) * R + r0 + tx] = f2bf(tile[tx][i]);
}

// ---------------- bf16 V-slice transpose: Ycat v -> VT[b,hk,d,s] ----------------
__global__ void k_vt(const short* __restrict__ Ycat, short* __restrict__ VT){
  __shared__ short tile[32][33];
  int b = blockIdx.z >> 2, hk = blockIdx.z & 3;
  int s0 = blockIdx.x * 32, d0 = blockIdx.y * 32;
  int tx = threadIdx.x, ty = threadIdx.y;   // (32, 8)
  #pragma unroll
  for (int i = ty; i < 32; i += 8)
    tile[i][tx] = Ycat[(size_t)(b * S_LEN + s0 + i) * LW + 9216 + hk * 256 + d0 + tx];
  __syncthreads();
  #pragma unroll
  for (int i = ty; i < 32; i += 8)
    VT[(size_t)((b * NKV + hk) * HDIM + d0 + i) * S_LEN + s0 + tx] = tile[tx][i];
}

// ================= 256x256 8-phase bf16 GEMM (T1+T2+T3/T4+T5) =================
#define MFMA_(a, b, c) __builtin_amdgcn_mfma_f32_16x16x32_bf16(a, b, c, 0, 0, 0)
#define LDA_(buf, ks, mh, f) (*(const bf16x8*)&As[buf][ks][(wm*128 + (mh)*64 + (f)*16 + l15) * 32 + rdSlot])
#define LDB_(buf, ks, f)     (*(const bf16x8*)&Bs[buf][ks][(wn*64  + (f)*16 + l15) * 32 + rdSlot])
#define STAGE_A_(buf, ks, tile) { \
  gload16(aG0 + (size_t)(tile)*64 + (ks)*32, &As[buf][ks][w*512]); \
  gload16(aG1 + (size_t)(tile)*64 + (ks)*32, &As[buf][ks][4096 + w*512]); }
#define STAGE_B_(buf, ks, tile) { \
  gload16(bG0 + (size_t)(tile)*64 + (ks)*32, &Bs[buf][ks][w*512]); \
  gload16(bG1 + (size_t)(tile)*64 + (ks)*32, &Bs[buf][ks][4096 + w*512]); }
#define VM4 asm volatile("s_waitcnt vmcnt(4)" ::: "memory");
#define PH_(buf, ks, mh, LB, ...) { \
  bf16x8 a0 = LDA_(buf,ks,mh,0), a1 = LDA_(buf,ks,mh,1), a2 = LDA_(buf,ks,mh,2), a3 = LDA_(buf,ks,mh,3); \
  if (LB) { b0 = LDB_(buf,ks,0); b1 = LDB_(buf,ks,1); b2 = LDB_(buf,ks,2); b3 = LDB_(buf,ks,3); } \
  __VA_ARGS__ \
  __builtin_amdgcn_s_barrier(); \
  asm volatile("s_waitcnt lgkmcnt(0)" ::: "memory"); \
  __builtin_amdgcn_s_setprio(1); \
  acc[(mh)*4+0][0] = MFMA_(a0, b0, acc[(mh)*4+0][0]); \
  acc[(mh)*4+0][1] = MFMA_(a0, b1, acc[(mh)*4+0][1]); \
  acc[(mh)*4+0][2] = MFMA_(a0, b2, acc[(mh)*4+0][2]); \
  acc[(mh)*4+0][3] = MFMA_(a0, b3, acc[(mh)*4+0][3]); \
  acc[(mh)*4+1][0] = MFMA_(a1, b0, acc[(mh)*4+1][0]); \
  acc[(mh)*4+1][1] = MFMA_(a1, b1, acc[(mh)*4+1][1]); \
  acc[(mh)*4+1][2] = MFMA_(a1, b2, acc[(mh)*4+1][2]); \
  acc[(mh)*4+1][3] = MFMA_(a1, b3, acc[(mh)*4+1][3]); \
  acc[(mh)*4+2][0] = MFMA_(a2, b0, acc[(mh)*4+2][0]); \
  acc[(mh)*4+2][1] = MFMA_(a2, b1, acc[(mh)*4+2][1]); \
  acc[(mh)*4+2][2] = MFMA_(a2, b2, acc[(mh)*4+2][2]); \
  acc[(mh)*4+2][3] = MFMA_(a2, b3, acc[(mh)*4+2][3]); \
  acc[(mh)*4+3][0] = MFMA_(a3, b0, acc[(mh)*4+3][0]); \
  acc[(mh)*4+3][1] = MFMA_(a3, b1, acc[(mh)*4+3][1]); \
  acc[(mh)*4+3][2] = MFMA_(a3, b2, acc[(mh)*4+3][2]); \
  acc[(mh)*4+3][3] = MFMA_(a3, b3, acc[(mh)*4+3][3]); \
  __builtin_amdgcn_s_setprio(0); \
  __builtin_amdgcn_s_barrier(); }

template<int OUTF32>
__global__ __launch_bounds__(512) void k_gemm2(const short* __restrict__ A,
                                               const short* __restrict__ BT,
                                               void* __restrict__ C,
                                               int M, int N, int K, int gx)
{
  __shared__ __align__(16) short As[2][2][8192];
  __shared__ __align__(16) short Bs[2][2][8192];
  const int t = threadIdx.x, lane = t & 63, w = t >> 6;
  const int l15 = lane & 15;
  const int wm = w >> 2, wn = w & 3;
  const int rdSlot = (((lane >> 4) ^ (lane & 3)) * 8);

  const int nwg = gridDim.x;
  const int swz = (blockIdx.x & 7) * (nwg >> 3) + (blockIdx.x >> 3);
  const int m0 = (swz / gx) * 256, n0 = (swz % gx) * 256;

  const int sRow = w * 16 + (lane >> 2);
  const int sSwz = ((lane & 3) ^ ((lane >> 2) & 3)) * 8;
  const short* aG0 = A  + (size_t)(m0 + sRow) * K + sSwz;
  const short* aG1 = A  + (size_t)(m0 + 128 + sRow) * K + sSwz;
  const short* bG0 = BT + (size_t)(n0 + sRow) * K + sSwz;
  const short* bG1 = BT + (size_t)(n0 + 128 + sRow) * K + sSwz;

  f32x4 acc[8][4] = {};
  bf16x8 b0 = {}, b1 = {}, b2 = {}, b3 = {};

  STAGE_A_(0, 0, 0) STAGE_A_(0, 1, 0) STAGE_B_(0, 0, 0) STAGE_B_(0, 1, 0)
  STAGE_A_(1, 0, 1) STAGE_B_(1, 0, 1)
  asm volatile("s_waitcnt vmcnt(4)" ::: "memory");
  __builtin_amdgcn_s_barrier();

  const int nIt = K >> 7;
  for (int i = 0; i < nIt; ++i) {
    const int c = 2 * i;
    const bool st = (i + 1 < nIt);
    PH_(0, 0, 0, 1, STAGE_A_(1, 1, c + 1))
    PH_(0, 0, 1, 0, STAGE_B_(1, 1, c + 1))
    PH_(0, 1, 0, 1, if (st) STAGE_A_(0, 0, c + 2))
    PH_(0, 1, 1, 0, if (st) STAGE_B_(0, 0, c + 2) VM4)
    PH_(1, 0, 0, 1, if (st) STAGE_A_(0, 1, c + 2))
    PH_(1, 0, 1, 0, if (st) STAGE_B_(0, 1, c + 2))
    PH_(1, 1, 0, 1, if (st) STAGE_A_(1, 0, c + 3))
    PH_(1, 1, 1, 0, if (st) STAGE_B_(1, 0, c + 3) VM4)
  }

  #pragma unroll
  for (int ii = 0; ii < 8; ++ii)
    #pragma unroll
    for (int r = 0; r < 4; ++r) {
      const int row = m0 + wm * 128 + ii * 16 + (lane >> 4) * 4 + r;
      #pragma unroll
      for (int j = 0; j < 4; ++j) {
        const int col = n0 + wn * 64 + j * 16 + l15;
        const float v = acc[ii][j][r];
        if (OUTF32) ((float*)C)[(size_t)row * N + col] = v;
        else        ((short*)C)[(size_t)row * N + col] = f2bf(v);
      }
    }
}

// ---------------- per-token: RMSNorm(q,k), gates, partial RoPE, in place ----------------
__global__ __launch_bounds__(256) void k_post(short* __restrict__ Ycat,
    const float* __restrict__ cosb, const float* __restrict__ sinb,
    const float* __restrict__ qw, const float* __restrict__ kw)
{
  const int tok = blockIdx.x;                 // b*S + s
  const int lane = threadIdx.x & 63, w = threadIdx.x >> 6;
  const size_t rowb = (size_t)tok * LW;
  const int d0 = lane * 4;

  float gq[4], gv[4];
  {
    s16x4 a  = *(const s16x4*)&Ycat[rowb + 10240 + d0];
    s16x4 bq = *(const s16x4*)&Ycat[rowb + 10240 + 256 + d0];
    #pragma unroll
    for (int j = 0; j < 4; ++j){ gq[j] = sigm(bf2f(a[j])); gv[j] = sigm(bf2f(bq[j])); }
  }
  float c4[4] = {0,0,0,0}, s4[4] = {0,0,0,0};
  if (lane < 16) {
    float4 c = *(const float4*)&cosb[(size_t)tok * 64 + d0];
    float4 s = *(const float4*)&sinb[(size_t)tok * 64 + d0];
    c4[0]=c.x; c4[1]=c.y; c4[2]=c.z; c4[3]=c.w;
    s4[0]=s.x; s4[1]=s.y; s4[2]=s.z; s4[3]=s.w;
  }
  float4 qv4 = *(const float4*)&qw[d0];
  float4 kv4 = *(const float4*)&kw[d0];
  float qwa[4] = {qv4.x, qv4.y, qv4.z, qv4.w};
  float kwa[4] = {kv4.x, kv4.y, kv4.z, kv4.w};

  #pragma unroll
  for (int hi = 0; hi < 4; ++hi) {
    const int hh = w * 4 + hi;
    const size_t off = rowb + hh * 512 + d0;
    s16x4 v = *(const s16x4*)&Ycat[off];
    float x[4];
    #pragma unroll
    for (int j = 0; j < 4; ++j) x[j] = bf2f(v[j]);
    float ss = x[0]*x[0] + x[1]*x[1] + x[2]*x[2] + x[3]*x[3];
    #pragma unroll
    for (int o2 = 1; o2 < 64; o2 <<= 1) ss += __shfl_xor(ss, o2);
    float rr = rsqrtf(ss * (1.0f/256.0f) + 1e-6f);
    #pragma unroll
    for (int j = 0; j < 4; ++j) x[j] = x[j] * rr * (1.0f + qwa[j]) * gq[j];
    float p[4];
    #pragma unroll
    for (int j = 0; j < 4; ++j) p[j] = __shfl_xor(x[j], 8);
    if (lane < 8)       { for (int j = 0; j < 4; ++j) x[j] = x[j]*c4[j] - p[j]*s4[j]; }
    else if (lane < 16) { for (int j = 0; j < 4; ++j) x[j] = x[j]*c4[j] + p[j]*s4[j]; }
    s16x4 o;
    #pragma unroll
    for (int j = 0; j < 4; ++j) o[j] = f2bf(x[j]);
    *(s16x4*)&Ycat[off] = o;
  }
  {
    const size_t off = rowb + 8192 + w * 256 + d0;
    s16x4 v = *(const s16x4*)&Ycat[off];
    float x[4];
    #pragma unroll
    for (int j = 0; j < 4; ++j) x[j] = bf2f(v[j]);
    float ss = x[0]*x[0] + x[1]*x[1] + x[2]*x[2] + x[3]*x[3];
    #pragma unroll
    for (int o2 = 1; o2 < 64; o2 <<= 1) ss += __shfl_xor(ss, o2);
    float rr = rsqrtf(ss * (1.0f/256.0f) + 1e-6f);
    #pragma unroll
    for (int j = 0; j < 4; ++j) x[j] = x[j] * rr * (1.0f + kwa[j]) * gq[j];
    float p[4];
    #pragma unroll
    for (int j = 0; j < 4; ++j) p[j] = __shfl_xor(x[j], 8);
    if (lane < 8)       { for (int j = 0; j < 4; ++j) x[j] = x[j]*c4[j] - p[j]*s4[j]; }
    else if (lane < 16) { for (int j = 0; j < 4; ++j) x[j] = x[j]*c4[j] + p[j]*s4[j]; }
    s16x4 o;
    #pragma unroll
    for (int j = 0; j < 4; ++j) o[j] = f2bf(x[j]);
    *(s16x4*)&Ycat[off] = o;
  }
  {
    const size_t off = rowb + 9216 + w * 256 + d0;
    s16x4 v = *(const s16x4*)&Ycat[off];
    s16x4 o;
    #pragma unroll
    for (int j = 0; j < 4; ++j) o[j] = f2bf(bf2f(v[j]) * gv[j]);
    *(s16x4*)&Ycat[off] = o;
  }
}

// ====== flash attention v3: swapped operands, per-wave rows, KVBLK=32 dbuf ======
// grid 1024: id = widx*8 + xcd; xcd=(b,hk); widx = head*32 + reversed q-block.
// Per wave: 16 q-rows (qrow = l15), O^T accum (d = jb*16 + g*4 + r, q = l15).
// QK^T swapped: sa[c] = mfma(K_frag, Q_frag) -> S[key, qrow=l15] lane-local rows.
// P wave-private in LDS (transpose only). K/V double-buffered, vmcnt(8) counted.
#define ATT_STAGE(bb, jj) { \
  _Pragma("unroll") \
  for (int ri = 0; ri < 4; ++ri) \
    gload16(kSrc + (size_t)((jj) + ri*8) * LW, &Ks[bb][t*8 + ri*2048]); \
  _Pragma("unroll") \
  for (int ri = 0; ri < 4; ++ri) \
    gload16(vSrc + (jj) + (size_t)(ri*64) * S_LEN, &Vs[bb][t*8 + ri*2048]); }

__global__ __launch_bounds__(256) void k_attn(const short* __restrict__ Ycat,
                                              const short* __restrict__ VT,
                                              short* __restrict__ AO)
{
  __shared__ __align__(16) short Ks[2][8192];   // [buf][32 rows x 256]
  __shared__ __align__(16) short Vs[2][8192];   // [buf][256 rows x 32]
  __shared__ __align__(16) short Ps[4][512];    // per-wave [16 rows x 32]

  const int t = threadIdx.x, lane = t & 63, w = t >> 6;
  const int l15 = lane & 15, g = lane >> 4;
  const int id = blockIdx.x;
  const int xcd = id & 7, widx = id >> 3;
  const int b = xcd >> 2, hk = xcd & 3;
  const int h = hk * 4 + (widx & 3);
  const int q0 = (31 - (widx >> 2)) * 64;
  const int qg = q0 + w * 16 + l15;        // this lane's q-row (global)
  const float SC2 = 0.09016844f;           // 1/16 * log2(e)

  // Q fragments (B-operand): lane holds Q[qrow=l15, d = kk*32 + g*8 .. +7]
  bf16x8 qf[8];
  {
    const size_t qb = ((size_t)(b * S_LEN) + qg) * LW + h * 512 + g * 8;
    #pragma unroll
    for (int kk = 0; kk < 8; ++kk)
      qf[kk] = *(const bf16x8*)&Ycat[qb + kk * 32];
  }
  asm volatile("s_waitcnt vmcnt(0)" ::: "memory");   // qf landed; counted scheme below

  // staging bases (source pre-swizzled; row&7 / row&3 invariant across rounds)
  const int kRow = t >> 5;
  const int kColS = ((((t & 31) * 16) ^ ((kRow & 7) << 4)) >> 1);
  const int vRow = t >> 2;
  const int vColS = ((((t & 3) * 16) ^ ((vRow & 3) << 4)) >> 1);
  const short* kSrc = Ycat + ((size_t)(b * S_LEN) + kRow) * LW + 8192 + hk * 256 + kColS;
  const short* vSrc = VT + ((size_t)((b * NKV + hk) * HDIM + vRow)) * S_LEN + vColS;

  f32x4 oacc[16] = {};
  float m_r = -1e30f, l_r = 0.0f;

  const int nt = (q0 >> 5) + 2;
  ATT_STAGE(0, 0)
  int buf = 0;
  char* Pw = (char*)Ps[w] + l15 * 64;
  const int pswz = (l15 & 3) << 4;

  for (int ti = 0; ti < nt; ++ti) {
    const int j0 = ti * 32;
    const int jn = (ti + 1 < nt) ? j0 + 32 : 0;   // dummy re-stage keeps vmcnt uniform
    ATT_STAGE(buf ^ 1, jn)
    asm volatile("s_waitcnt vmcnt(8)" ::: "memory");
    __builtin_amdgcn_s_barrier();

    if (j0 <= q0 + w * 16 + 15) {                 // wave-uniform causal skip
      // ---- QK^T swapped: sa[c] lane holds S[key = j0+c*16+g*4+r, qrow = l15]
      f32x4 sa[2] = {};
      #pragma unroll
      for (int kk = 0; kk < 8; ++kk) {
        #pragma unroll
        for (int c = 0; c < 2; ++c) {
          const int row = c * 16 + l15;
          bf16x8 kf = *(const bf16x8*)((const char*)Ks[buf] + row * 512
                       + ((kk * 64 + g * 16) ^ ((l15 & 7) << 4)));
          sa[c] = __builtin_amdgcn_mfma_f32_16x16x32_bf16(kf, qf[kk], sa[c], 0, 0, 0);
        }
      }
      // ---- in-lane softmax over this lane's 8 keys (row stats via 2 shfl)
      float s[8];
      #pragma unroll
      for (int c = 0; c < 2; ++c)
        #pragma unroll
        for (int r = 0; r < 4; ++r) s[c * 4 + r] = sa[c][r];
      if (j0 + 31 > qg) {
        #pragma unroll
        for (int c = 0; c < 2; ++c)
          #pragma unroll
          for (int r = 0; r < 4; ++r)
            if (j0 + c * 16 + g * 4 + r > qg) s[c * 4 + r] = -1e30f;
      }
      float mx = s[0];
      #pragma unroll
      for (int i = 1; i < 8; ++i) mx = fmaxf(mx, s[i]);
      mx = fmaxf(mx, __shfl_xor(mx, 16));
      mx = fmaxf(mx, __shfl_xor(mx, 32));
      if (!__all(mx - m_r <= 128.0f)) {           // T13 defer-max
        const float mnew = fmaxf(m_r, mx);
        const float alpha = exp2f((m_r - mnew) * SC2);
        l_r *= alpha;
        #pragma unroll
        for (int jb = 0; jb < 16; ++jb)
          #pragma unroll
          for (int r = 0; r < 4; ++r) oacc[jb][r] *= alpha;
        m_r = mnew;
      }
      float p[8], rs = 0.0f;
      #pragma unroll
      for (int i = 0; i < 8; ++i) { p[i] = exp2f((s[i] - m_r) * SC2); rs += p[i]; }
      rs += __shfl_xor(rs, 16);
      rs += __shfl_xor(rs, 32);
      l_r += rs;
      // ---- P pack (bf16 pairs) -> wave-private LDS, swizzled
      #pragma unroll
      for (int c = 0; c < 2; ++c) {
        uint2 u;
        u.x = (unsigned short)f2bf(p[c*4+0]) | ((unsigned)(unsigned short)f2bf(p[c*4+1]) << 16);
        u.y = (unsigned short)f2bf(p[c*4+2]) | ((unsigned)(unsigned short)f2bf(p[c*4+3]) << 16);
        *(uint2*)(Pw + ((c * 32 + 8 * g) ^ pswz)) = u;
      }
      bf16x8 pa = *(const bf16x8*)(Pw + ((16 * g) ^ pswz));   // keys g*8..+7
      // ---- PV swapped: oacc[jb] += mfma(V^T_frag, P^T_frag); d = jb*16+g*4+r
      #pragma unroll
      for (int jb = 0; jb < 16; ++jb) {
        const int vrow = jb * 16 + l15;
        bf16x8 vf = *(const bf16x8*)((const char*)Vs[buf] + vrow * 64
                     + ((16 * g) ^ ((l15 & 3) << 4)));
        oacc[jb] = __builtin_amdgcn_mfma_f32_16x16x32_bf16(vf, pa, oacc[jb], 0, 0, 0);
      }
    }
    __builtin_amdgcn_s_barrier();
    buf ^= 1;
  }
  asm volatile("s_waitcnt vmcnt(0)" ::: "memory");  // drain dummy stage

  // ---- epilogue: O/l * sigmoid(gate), packed 8B stores; all lane-local
  const float linv = 1.0f / l_r;
  const size_t gb = ((size_t)(b * S_LEN) + qg) * LW + h * 512 + 256;
  const size_t ob = ((size_t)(b * S_LEN) + qg) * 4096 + h * 256;
  #pragma unroll
  for (int jb = 0; jb < 16; ++jb) {
    const int d0 = jb * 16 + g * 4;
    s16x4 gt = *(const s16x4*)&Ycat[gb + d0];
    s16x4 o;
    #pragma unroll
    for (int r = 0; r < 4; ++r)
      o[r] = f2bf(oacc[jb][r] * linv * sigm(bf2f(gt[r])));
    *(s16x4*)&AO[ob + d0] = o;
  }
}

extern "C" void kernel_launch(void* const* d_in, const int* in_sizes, int n_in,
                              void* d_out, int out_size, void* d_ws, size_t ws_size,
                              hipStream_t stream) {
  const float* X    = (const float*)d_in[0];
  const float* cosb = (const float*)d_in[1];
  const float* sinb = (const float*)d_in[2];
  const float* Wq   = (const float*)d_in[4];
  const float* Wk   = (const float*)d_in[5];
  const float* Wv   = (const float*)d_in[6];
  const float* Wo   = (const float*)d_in[7];
  const float* qw   = (const float*)d_in[8];
  const float* kw   = (const float*)d_in[9];
  const float* Wr   = (const float*)d_in[10];

  short* Xb    = (short*)d_ws;                       //  8,388,608
  short* WcatT = Xb    +  8388608;                   // 22,020,096
  short* AO    = WcatT;                              // alias (dead after GEMM0)
  short* WoT   = WcatT + 22020096;                   //  8,388,608
  short* Ycat  = WoT   +  8388608;                   // 44,040,192
  short* VT    = Ycat  + 44040192;                   //  4,194,304

  dim3 tb(32, 8);
  k_cvt<<<8192, 256, 0, stream>>>(X, Xb, 2097152);
  k_tcvt<<<dim3(256, 64), tb, 0, stream>>>(Wq, WcatT,                      2048, 8192);
  k_tcvt<<<dim3( 32, 64), tb, 0, stream>>>(Wk, WcatT + (size_t)8192*2048,  2048, 1024);
  k_tcvt<<<dim3( 32, 64), tb, 0, stream>>>(Wv, WcatT + (size_t)9216*2048,  2048, 1024);
  k_tcvt<<<dim3( 16, 64), tb, 0, stream>>>(Wr, WcatT + (size_t)10240*2048, 2048,  512);
  k_tcvt<<<dim3( 64,128), tb, 0, stream>>>(Wo, WoT,                        4096, 2048);

  k_gemm2<0><<<672, 512, 0, stream>>>(Xb, WcatT, Ycat, 4096, 10752, 2048, 42);
  k_post<<<4096, 256, 0, stream>>>(Ycat, cosb, sinb, qw, kw);
  k_vt<<<dim3(64, 8, 8), tb, 0, stream>>>(Ycat, VT);
  k_attn<<<1024, 256, 0, stream>>>(Ycat, VT, AO);
  k_gemm2<1><<<128, 512, 0, stream>>>(AO, WoT, d_out, 4096, 2048, 4096, 8);
}

// Round 5
// 537.164 us; speedup vs baseline: 1.5626x; 1.0273x over previous
//
#include <hip/hip_runtime.h>

#define S_LEN 2048
#define NB    2
#define NH    16
#define NKV   4
#define HDIM  256
#define LW    10752   // Ycat row width: 8192 (q|gate) + 1024 (k) + 1024 (v) + 512 (r)

using bf16x8 = __attribute__((ext_vector_type(8))) short;
using s16x4  = __attribute__((ext_vector_type(4))) short;
using f32x4  = __attribute__((ext_vector_type(4))) float;

__device__ __forceinline__ float bf2f(short u){
  union { float f; unsigned u; } x; x.u = ((unsigned)(unsigned short)u) << 16; return x.f;
}
__device__ __forceinline__ short f2bf(float f){
  unsigned i = __builtin_bit_cast(unsigned, f);
  unsigned r = (i + 0x7fffu + ((i >> 16) & 1u)) >> 16;
  return (short)r;
}
__device__ __forceinline__ float sigm(float x){ return 1.0f / (1.0f + __expf(-x)); }

__device__ __forceinline__ void gload16(const short* g, short* lds){
  __builtin_amdgcn_global_load_lds((const __attribute__((address_space(1))) void*)g,
                                   (__attribute__((address_space(3))) void*)lds,
                                   16, 0, 0);
}

// ---------------- f32 -> bf16 elementwise ----------------
__global__ void k_cvt(const float* __restrict__ in, short* __restrict__ out, int n4){
  int i = blockIdx.x * blockDim.x + threadIdx.x;
  if (i >= n4) return;
  float4 v = ((const float4*)in)[i];
  s16x4 o;
  o[0] = f2bf(v.x); o[1] = f2bf(v.y); o[2] = f2bf(v.z); o[3] = f2bf(v.w);
  ((s16x4*)out)[i] = o;
}

// ------- fused weight transpose+convert: 5 matrices, one launch -------
// f32 (R,C) -> bf16 (C,R). Tile ids: [0,e0) Wq, [e0,e1) Wk, [e1,e2) Wv,
// [e2,e3) Wr, [e3,e4) Wo. Uniform branch per block.
__global__ void k_wt(const float* __restrict__ Wq, const float* __restrict__ Wk,
                     const float* __restrict__ Wv, const float* __restrict__ Wr,
                     const float* __restrict__ Wo, short* __restrict__ WcatT,
                     short* __restrict__ WoT)
{
  __shared__ float tile[32][33];
  const int id = blockIdx.x;
  const float* src; short* dst; int R, C, Ct, local;
  if (id < 16384)      { src = Wq; dst = WcatT;                      R = 2048; C = 8192; Ct = 256; local = id; }
  else if (id < 18432) { src = Wk; dst = WcatT + (size_t)8192*2048;  R = 2048; C = 1024; Ct =  32; local = id - 16384; }
  else if (id < 20480) { src = Wv; dst = WcatT + (size_t)9216*2048;  R = 2048; C = 1024; Ct =  32; local = id - 18432; }
  else if (id < 21504) { src = Wr; dst = WcatT + (size_t)10240*2048; R = 2048; C =  512; Ct =  16; local = id - 20480; }
  else                 { src = Wo; dst = WoT;                        R = 4096; C = 2048; Ct =  64; local = id - 21504; }
  const int c0 = (local % Ct) * 32, r0 = (local / Ct) * 32;
  const int tx = threadIdx.x, ty = threadIdx.y;   // (32, 8)
  #pragma unroll
  for (int i = ty; i < 32; i += 8)
    tile[i][tx] = src[(size_t)(r0 + i) * C + c0 + tx];
  __syncthreads();
  #pragma unroll
  for (int i = ty; i < 32; i += 8)
    dst[(size_t)(c0 + i) * R + r0 + tx] = f2bf(tile[tx][i]);
}

// ---------------- bf16 V-slice transpose: Ycat v -> VT[b,hk,d,s] ----------------
__global__ void k_vt(const short* __restrict__ Ycat, short* __restrict__ VT){
  __shared__ short tile[32][33];
  int b = blockIdx.z >> 2, hk = blockIdx.z & 3;
  int s0 = blockIdx.x * 32, d0 = blockIdx.y * 32;
  int tx = threadIdx.x, ty = threadIdx.y;   // (32, 8)
  #pragma unroll
  for (int i = ty; i < 32; i += 8)
    tile[i][tx] = Ycat[(size_t)(b * S_LEN + s0 + i) * LW + 9216 + hk * 256 + d0 + tx];
  __syncthreads();
  #pragma unroll
  for (int i = ty; i < 32; i += 8)
    VT[(size_t)((b * NKV + hk) * HDIM + d0 + i) * S_LEN + s0 + tx] = tile[tx][i];
}

// ================= 256x256 8-phase bf16 GEMM (T1+T2+T3/T4+T5) =================
// Read/write swizzle: f(row) = (row>>1)&3 -> 2-way max under 16-lane phasing.
#define MFMA_(a, b, c) __builtin_amdgcn_mfma_f32_16x16x32_bf16(a, b, c, 0, 0, 0)
#define LDA_(buf, ks, mh, f) (*(const bf16x8*)&As[buf][ks][(wm*128 + (mh)*64 + (f)*16 + l15) * 32 + rdSlot])
#define LDB_(buf, ks, f)     (*(const bf16x8*)&Bs[buf][ks][(wn*64  + (f)*16 + l15) * 32 + rdSlot])
#define STAGE_A_(buf, ks, tile) { \
  gload16(aG0 + (size_t)(tile)*64 + (ks)*32, &As[buf][ks][w*512]); \
  gload16(aG1 + (size_t)(tile)*64 + (ks)*32, &As[buf][ks][4096 + w*512]); }
#define STAGE_B_(buf, ks, tile) { \
  gload16(bG0 + (size_t)(tile)*64 + (ks)*32, &Bs[buf][ks][w*512]); \
  gload16(bG1 + (size_t)(tile)*64 + (ks)*32, &Bs[buf][ks][4096 + w*512]); }
#define VM4 asm volatile("s_waitcnt vmcnt(4)" ::: "memory");
#define PH_(buf, ks, mh, LB, ...) { \
  bf16x8 a0 = LDA_(buf,ks,mh,0), a1 = LDA_(buf,ks,mh,1), a2 = LDA_(buf,ks,mh,2), a3 = LDA_(buf,ks,mh,3); \
  if (LB) { b0 = LDB_(buf,ks,0); b1 = LDB_(buf,ks,1); b2 = LDB_(buf,ks,2); b3 = LDB_(buf,ks,3); } \
  __VA_ARGS__ \
  __builtin_amdgcn_s_barrier(); \
  asm volatile("s_waitcnt lgkmcnt(0)" ::: "memory"); \
  __builtin_amdgcn_s_setprio(1); \
  acc[(mh)*4+0][0] = MFMA_(a0, b0, acc[(mh)*4+0][0]); \
  acc[(mh)*4+0][1] = MFMA_(a0, b1, acc[(mh)*4+0][1]); \
  acc[(mh)*4+0][2] = MFMA_(a0, b2, acc[(mh)*4+0][2]); \
  acc[(mh)*4+0][3] = MFMA_(a0, b3, acc[(mh)*4+0][3]); \
  acc[(mh)*4+1][0] = MFMA_(a1, b0, acc[(mh)*4+1][0]); \
  acc[(mh)*4+1][1] = MFMA_(a1, b1, acc[(mh)*4+1][1]); \
  acc[(mh)*4+1][2] = MFMA_(a1, b2, acc[(mh)*4+1][2]); \
  acc[(mh)*4+1][3] = MFMA_(a1, b3, acc[(mh)*4+1][3]); \
  acc[(mh)*4+2][0] = MFMA_(a2, b0, acc[(mh)*4+2][0]); \
  acc[(mh)*4+2][1] = MFMA_(a2, b1, acc[(mh)*4+2][1]); \
  acc[(mh)*4+2][2] = MFMA_(a2, b2, acc[(mh)*4+2][2]); \
  acc[(mh)*4+2][3] = MFMA_(a2, b3, acc[(mh)*4+2][3]); \
  acc[(mh)*4+3][0] = MFMA_(a3, b0, acc[(mh)*4+3][0]); \
  acc[(mh)*4+3][1] = MFMA_(a3, b1, acc[(mh)*4+3][1]); \
  acc[(mh)*4+3][2] = MFMA_(a3, b2, acc[(mh)*4+3][2]); \
  acc[(mh)*4+3][3] = MFMA_(a3, b3, acc[(mh)*4+3][3]); \
  __builtin_amdgcn_s_setprio(0); \
  __builtin_amdgcn_s_barrier(); }

template<int OUTF32, int CM>
__global__ __launch_bounds__(512) void k_gemm2(const short* __restrict__ A,
                                               const short* __restrict__ BT,
                                               void* __restrict__ C,
                                               int M, int N, int K, int gx)
{
  __shared__ __align__(16) short As[2][2][8192];
  __shared__ __align__(16) short Bs[2][2][8192];
  const int t = threadIdx.x, lane = t & 63, w = t >> 6;
  const int l15 = lane & 15;
  const int wm = w >> 2, wn = w & 3;
  const int rdSlot = (((lane >> 4) ^ ((lane >> 1) & 3)) * 8);

  // XCD-aware bijective swizzle (nwg % 8 == 0 at both call sites)
  const int nwg = gridDim.x;
  const int swz = (blockIdx.x & 7) * (nwg >> 3) + (blockIdx.x >> 3);
  // CM=1: column-major decode (XCD owns an N-slice; B-reuse). CM=0: row-major.
  const int m0 = (CM ? (swz % gx) : (swz / gx)) * 256;
  const int n0 = (CM ? (swz / gx) : (swz % gx)) * 256;

  const int sRow = w * 16 + (lane >> 2);
  const int sSwz = ((lane & 3) ^ ((lane >> 3) & 3)) * 8;
  const short* aG0 = A  + (size_t)(m0 + sRow) * K + sSwz;
  const short* aG1 = A  + (size_t)(m0 + 128 + sRow) * K + sSwz;
  const short* bG0 = BT + (size_t)(n0 + sRow) * K + sSwz;
  const short* bG1 = BT + (size_t)(n0 + 128 + sRow) * K + sSwz;

  f32x4 acc[8][4] = {};
  bf16x8 b0 = {}, b1 = {}, b2 = {}, b3 = {};

  STAGE_A_(0, 0, 0) STAGE_A_(0, 1, 0) STAGE_B_(0, 0, 0) STAGE_B_(0, 1, 0)
  STAGE_A_(1, 0, 1) STAGE_B_(1, 0, 1)
  asm volatile("s_waitcnt vmcnt(4)" ::: "memory");
  __builtin_amdgcn_s_barrier();

  const int nIt = K >> 7;
  for (int i = 0; i < nIt; ++i) {
    const int c = 2 * i;
    const bool st = (i + 1 < nIt);
    PH_(0, 0, 0, 1, STAGE_A_(1, 1, c + 1))
    PH_(0, 0, 1, 0, STAGE_B_(1, 1, c + 1))
    PH_(0, 1, 0, 1, if (st) STAGE_A_(0, 0, c + 2))
    PH_(0, 1, 1, 0, if (st) STAGE_B_(0, 0, c + 2) VM4)
    PH_(1, 0, 0, 1, if (st) STAGE_A_(0, 1, c + 2))
    PH_(1, 0, 1, 0, if (st) STAGE_B_(0, 1, c + 2))
    PH_(1, 1, 0, 1, if (st) STAGE_A_(1, 0, c + 3))
    PH_(1, 1, 1, 0, if (st) STAGE_B_(1, 0, c + 3) VM4)
  }

  #pragma unroll
  for (int ii = 0; ii < 8; ++ii)
    #pragma unroll
    for (int r = 0; r < 4; ++r) {
      const int row = m0 + wm * 128 + ii * 16 + (lane >> 4) * 4 + r;
      #pragma unroll
      for (int j = 0; j < 4; ++j) {
        const int col = n0 + wn * 64 + j * 16 + l15;
        const float v = acc[ii][j][r];
        if (OUTF32) ((float*)C)[(size_t)row * N + col] = v;
        else        ((short*)C)[(size_t)row * N + col] = f2bf(v);
      }
    }
}

// ---------------- per-token: RMSNorm(q,k), gates, partial RoPE, in place ----------------
__global__ __launch_bounds__(256) void k_post(short* __restrict__ Ycat,
    const float* __restrict__ cosb, const float* __restrict__ sinb,
    const float* __restrict__ qw, const float* __restrict__ kw)
{
  const int tok = blockIdx.x;                 // b*S + s
  const int lane = threadIdx.x & 63, w = threadIdx.x >> 6;
  const size_t rowb = (size_t)tok * LW;
  const int d0 = lane * 4;

  float gq[4], gv[4];
  {
    s16x4 a  = *(const s16x4*)&Ycat[rowb + 10240 + d0];
    s16x4 bq = *(const s16x4*)&Ycat[rowb + 10240 + 256 + d0];
    #pragma unroll
    for (int j = 0; j < 4; ++j){ gq[j] = sigm(bf2f(a[j])); gv[j] = sigm(bf2f(bq[j])); }
  }
  float c4[4] = {0,0,0,0}, s4[4] = {0,0,0,0};
  if (lane < 16) {
    float4 c = *(const float4*)&cosb[(size_t)tok * 64 + d0];
    float4 s = *(const float4*)&sinb[(size_t)tok * 64 + d0];
    c4[0]=c.x; c4[1]=c.y; c4[2]=c.z; c4[3]=c.w;
    s4[0]=s.x; s4[1]=s.y; s4[2]=s.z; s4[3]=s.w;
  }
  float4 qv4 = *(const float4*)&qw[d0];
  float4 kv4 = *(const float4*)&kw[d0];
  float qwa[4] = {qv4.x, qv4.y, qv4.z, qv4.w};
  float kwa[4] = {kv4.x, kv4.y, kv4.z, kv4.w};

  #pragma unroll
  for (int hi = 0; hi < 4; ++hi) {
    const int hh = w * 4 + hi;
    const size_t off = rowb + hh * 512 + d0;
    s16x4 v = *(const s16x4*)&Ycat[off];
    float x[4];
    #pragma unroll
    for (int j = 0; j < 4; ++j) x[j] = bf2f(v[j]);
    float ss = x[0]*x[0] + x[1]*x[1] + x[2]*x[2] + x[3]*x[3];
    #pragma unroll
    for (int o2 = 1; o2 < 64; o2 <<= 1) ss += __shfl_xor(ss, o2);
    float rr = rsqrtf(ss * (1.0f/256.0f) + 1e-6f);
    #pragma unroll
    for (int j = 0; j < 4; ++j) x[j] = x[j] * rr * (1.0f + qwa[j]) * gq[j];
    float p[4];
    #pragma unroll
    for (int j = 0; j < 4; ++j) p[j] = __shfl_xor(x[j], 8);
    if (lane < 8)       { for (int j = 0; j < 4; ++j) x[j] = x[j]*c4[j] - p[j]*s4[j]; }
    else if (lane < 16) { for (int j = 0; j < 4; ++j) x[j] = x[j]*c4[j] + p[j]*s4[j]; }
    s16x4 o;
    #pragma unroll
    for (int j = 0; j < 4; ++j) o[j] = f2bf(x[j]);
    *(s16x4*)&Ycat[off] = o;
  }
  {
    const size_t off = rowb + 8192 + w * 256 + d0;
    s16x4 v = *(const s16x4*)&Ycat[off];
    float x[4];
    #pragma unroll
    for (int j = 0; j < 4; ++j) x[j] = bf2f(v[j]);
    float ss = x[0]*x[0] + x[1]*x[1] + x[2]*x[2] + x[3]*x[3];
    #pragma unroll
    for (int o2 = 1; o2 < 64; o2 <<= 1) ss += __shfl_xor(ss, o2);
    float rr = rsqrtf(ss * (1.0f/256.0f) + 1e-6f);
    #pragma unroll
    for (int j = 0; j < 4; ++j) x[j] = x[j] * rr * (1.0f + kwa[j]) * gq[j];
    float p[4];
    #pragma unroll
    for (int j = 0; j < 4; ++j) p[j] = __shfl_xor(x[j], 8);
    if (lane < 8)       { for (int j = 0; j < 4; ++j) x[j] = x[j]*c4[j] - p[j]*s4[j]; }
    else if (lane < 16) { for (int j = 0; j < 4; ++j) x[j] = x[j]*c4[j] + p[j]*s4[j]; }
    s16x4 o;
    #pragma unroll
    for (int j = 0; j < 4; ++j) o[j] = f2bf(x[j]);
    *(s16x4*)&Ycat[off] = o;
  }
  {
    const size_t off = rowb + 9216 + w * 256 + d0;
    s16x4 v = *(const s16x4*)&Ycat[off];
    s16x4 o;
    #pragma unroll
    for (int j = 0; j < 4; ++j) o[j] = f2bf(bf2f(v[j]) * gv[j]);
    *(s16x4*)&Ycat[off] = o;
  }
}

// ====== flash attention: swapped operands, per-wave rows, KVBLK=32 dbuf ======
// Balanced q-block mapping: coset {31-q, 16+q, 15-q, q} sums const (62) for any
// 4 blocks strided by 32 in widx; heavy blocks dispatch first (greedy LPT).
#define ATT_STAGE(bb, jj) { \
  _Pragma("unroll") \
  for (int ri = 0; ri < 4; ++ri) \
    gload16(kSrc + (size_t)((jj) + ri*8) * LW, &Ks[bb][t*8 + ri*2048]); \
  _Pragma("unroll") \
  for (int ri = 0; ri < 4; ++ri) \
    gload16(vSrc + (jj) + (size_t)(ri*64) * S_LEN, &Vs[bb][t*8 + ri*2048]); }

__global__ __launch_bounds__(256) void k_attn(const short* __restrict__ Ycat,
                                              const short* __restrict__ VT,
                                              short* __restrict__ AO)
{
  __shared__ __align__(16) short Ks[2][8192];   // [buf][32 rows x 256]
  __shared__ __align__(16) short Vs[2][8192];   // [buf][256 rows x 32]
  __shared__ __align__(16) short Ps[4][512];    // per-wave [16 rows x 32]

  const int t = threadIdx.x, lane = t & 63, w = t >> 6;
  const int l15 = lane & 15, g = lane >> 4;
  const int id = blockIdx.x;
  const int xcd = id & 7, widx = id >> 3;
  const int b = xcd >> 2, hk = xcd & 3;
  const int h = hk * 4 + (widx & 3);
  const int x = widx >> 2, qq = x & 7, jj = x >> 3;
  const int qsel = (jj == 0) ? 31 - qq : (jj == 1) ? 16 + qq : (jj == 2) ? 15 - qq : qq;
  const int q0 = qsel * 64;
  const int qg = q0 + w * 16 + l15;        // this lane's q-row (global)
  const float SC2 = 0.09016844f;           // 1/16 * log2(e)

  // Q fragments (B-operand): lane holds Q[qrow=l15, d = kk*32 + g*8 .. +7]
  bf16x8 qf[8];
  {
    const size_t qb = ((size_t)(b * S_LEN) + qg) * LW + h * 512 + g * 8;
    #pragma unroll
    for (int kk = 0; kk < 8; ++kk)
      qf[kk] = *(const bf16x8*)&Ycat[qb + kk * 32];
  }
  asm volatile("s_waitcnt vmcnt(0)" ::: "memory");

  const int kRow = t >> 5;
  const int kColS = ((((t & 31) * 16) ^ ((kRow & 7) << 4)) >> 1);
  const int vRow = t >> 2;
  const int vColS = ((((t & 3) * 16) ^ ((vRow & 3) << 4)) >> 1);
  const short* kSrc = Ycat + ((size_t)(b * S_LEN) + kRow) * LW + 8192 + hk * 256 + kColS;
  const short* vSrc = VT + ((size_t)((b * NKV + hk) * HDIM + vRow)) * S_LEN + vColS;

  f32x4 oacc[16] = {};
  float m_r = -1e30f, l_r = 0.0f;

  const int nt = (q0 >> 5) + 2;
  ATT_STAGE(0, 0)
  int buf = 0;
  char* Pw = (char*)Ps[w] + l15 * 64;
  const int pswz = (l15 & 3) << 4;

  for (int ti = 0; ti < nt; ++ti) {
    const int j0 = ti * 32;
    const int jn = (ti + 1 < nt) ? j0 + 32 : 0;   // dummy re-stage keeps vmcnt uniform
    ATT_STAGE(buf ^ 1, jn)
    asm volatile("s_waitcnt vmcnt(8)" ::: "memory");
    __builtin_amdgcn_s_barrier();

    if (j0 <= q0 + w * 16 + 15) {                 // wave-uniform causal skip
      f32x4 sa[2] = {};
      #pragma unroll
      for (int kk = 0; kk < 8; ++kk) {
        #pragma unroll
        for (int c = 0; c < 2; ++c) {
          const int row = c * 16 + l15;
          bf16x8 kf = *(const bf16x8*)((const char*)Ks[buf] + row * 512
                       + ((kk * 64 + g * 16) ^ ((l15 & 7) << 4)));
          sa[c] = __builtin_amdgcn_mfma_f32_16x16x32_bf16(kf, qf[kk], sa[c], 0, 0, 0);
        }
      }
      float s[8];
      #pragma unroll
      for (int c = 0; c < 2; ++c)
        #pragma unroll
        for (int r = 0; r < 4; ++r) s[c * 4 + r] = sa[c][r];
      if (j0 + 31 > qg) {
        #pragma unroll
        for (int c = 0; c < 2; ++c)
          #pragma unroll
          for (int r = 0; r < 4; ++r)
            if (j0 + c * 16 + g * 4 + r > qg) s[c * 4 + r] = -1e30f;
      }
      float mx = s[0];
      #pragma unroll
      for (int i = 1; i < 8; ++i) mx = fmaxf(mx, s[i]);
      mx = fmaxf(mx, __shfl_xor(mx, 16));
      mx = fmaxf(mx, __shfl_xor(mx, 32));
      if (!__all(mx - m_r <= 128.0f)) {           // T13 defer-max
        const float mnew = fmaxf(m_r, mx);
        const float alpha = exp2f((m_r - mnew) * SC2);
        l_r *= alpha;
        #pragma unroll
        for (int jb = 0; jb < 16; ++jb)
          #pragma unroll
          for (int r = 0; r < 4; ++r) oacc[jb][r] *= alpha;
        m_r = mnew;
      }
      float p[8], rs = 0.0f;
      #pragma unroll
      for (int i = 0; i < 8; ++i) { p[i] = exp2f((s[i] - m_r) * SC2); rs += p[i]; }
      rs += __shfl_xor(rs, 16);
      rs += __shfl_xor(rs, 32);
      l_r += rs;
      #pragma unroll
      for (int c = 0; c < 2; ++c) {
        uint2 u;
        u.x = (unsigned short)f2bf(p[c*4+0]) | ((unsigned)(unsigned short)f2bf(p[c*4+1]) << 16);
        u.y = (unsigned short)f2bf(p[c*4+2]) | ((unsigned)(unsigned short)f2bf(p[c*4+3]) << 16);
        *(uint2*)(Pw + ((c * 32 + 8 * g) ^ pswz)) = u;
      }
      bf16x8 pa = *(const bf16x8*)(Pw + ((16 * g) ^ pswz));   // keys g*8..+7
      #pragma unroll
      for (int jb = 0; jb < 16; ++jb) {
        const int vrow = jb * 16 + l15;
        bf16x8 vf = *(const bf16x8*)((const char*)Vs[buf] + vrow * 64
                     + ((16 * g) ^ ((l15 & 3) << 4)));
        oacc[jb] = __builtin_amdgcn_mfma_f32_16x16x32_bf16(vf, pa, oacc[jb], 0, 0, 0);
      }
    }
    __builtin_amdgcn_s_barrier();
    buf ^= 1;
  }
  asm volatile("s_waitcnt vmcnt(0)" ::: "memory");  // drain dummy stage

  const float linv = 1.0f / l_r;
  const size_t gb = ((size_t)(b * S_LEN) + qg) * LW + h * 512 + 256;
  const size_t ob = ((size_t)(b * S_LEN) + qg) * 4096 + h * 256;
  #pragma unroll
  for (int jb = 0; jb < 16; ++jb) {
    const int d0 = jb * 16 + g * 4;
    s16x4 gt = *(const s16x4*)&Ycat[gb + d0];
    s16x4 o;
    #pragma unroll
    for (int r = 0; r < 4; ++r)
      o[r] = f2bf(oacc[jb][r] * linv * sigm(bf2f(gt[r])));
    *(s16x4*)&AO[ob + d0] = o;
  }
}

extern "C" void kernel_launch(void* const* d_in, const int* in_sizes, int n_in,
                              void* d_out, int out_size, void* d_ws, size_t ws_size,
                              hipStream_t stream) {
  const float* X    = (const float*)d_in[0];
  const float* cosb = (const float*)d_in[1];
  const float* sinb = (const float*)d_in[2];
  const float* Wq   = (const float*)d_in[4];
  const float* Wk   = (const float*)d_in[5];
  const float* Wv   = (const float*)d_in[6];
  const float* Wo   = (const float*)d_in[7];
  const float* qw   = (const float*)d_in[8];
  const float* kw   = (const float*)d_in[9];
  const float* Wr   = (const float*)d_in[10];

  short* Xb    = (short*)d_ws;                       //  8,388,608
  short* WcatT = Xb    +  8388608;                   // 22,020,096
  short* AO    = WcatT;                              // alias (dead after GEMM0)
  short* WoT   = WcatT + 22020096;                   //  8,388,608
  short* Ycat  = WoT   +  8388608;                   // 44,040,192
  short* VT    = Ycat  + 44040192;                   //  4,194,304

  dim3 tb(32, 8);
  k_cvt<<<8192, 256, 0, stream>>>(X, Xb, 2097152);
  k_wt<<<29696, tb, 0, stream>>>(Wq, Wk, Wv, Wr, Wo, WcatT, WoT);

  k_gemm2<0, 1><<<672, 512, 0, stream>>>(Xb, WcatT, Ycat, 4096, 10752, 2048, 16);
  k_post<<<4096, 256, 0, stream>>>(Ycat, cosb, sinb, qw, kw);
  k_vt<<<dim3(64, 8, 8), tb, 0, stream>>>(Ycat, VT);
  k_attn<<<1024, 256, 0, stream>>>(Ycat, VT, AO);
  k_gemm2<1, 0><<<128, 512, 0, stream>>>(AO, WoT, d_out, 4096, 2048, 4096, 8);
}

// Round 7
// 502.211 us; speedup vs baseline: 1.6713x; 1.0696x over previous
//
#include <hip/hip_runtime.h>

#define S_LEN 2048
#define NB    2
#define NH    16
#define NKV   4
#define HDIM  256
#define LW    10752   // Ycat row width: 8192 (q|gate) + 1024 (k) + 1024 (v) + 512 (r)

using bf16x8 = __attribute__((ext_vector_type(8))) short;
using s16x4  = __attribute__((ext_vector_type(4))) short;
using f32x4  = __attribute__((ext_vector_type(4))) float;

__device__ __forceinline__ float bf2f(short u){
  union { float f; unsigned u; } x; x.u = ((unsigned)(unsigned short)u) << 16; return x.f;
}
__device__ __forceinline__ short f2bf(float f){
  unsigned i = __builtin_bit_cast(unsigned, f);
  unsigned r = (i + 0x7fffu + ((i >> 16) & 1u)) >> 16;
  return (short)r;
}
__device__ __forceinline__ float sigm(float x){ return 1.0f / (1.0f + __expf(-x)); }

__device__ __forceinline__ void gload16(const short* g, short* lds){
  __builtin_amdgcn_global_load_lds((const __attribute__((address_space(1))) void*)g,
                                   (__attribute__((address_space(3))) void*)lds,
                                   16, 0, 0);
}

// ---------------- f32 -> bf16 elementwise ----------------
__global__ void k_cvt(const float* __restrict__ in, short* __restrict__ out, int n4){
  int i = blockIdx.x * blockDim.x + threadIdx.x;
  if (i >= n4) return;
  float4 v = ((const float4*)in)[i];
  s16x4 o;
  o[0] = f2bf(v.x); o[1] = f2bf(v.y); o[2] = f2bf(v.z); o[3] = f2bf(v.w);
  ((s16x4*)out)[i] = o;
}

// ---------------- split-K reduce: o += b (n4 = float4 count!) ----------------
__global__ void k_add(const float* __restrict__ b, float* __restrict__ o, int n4){
  int i = blockIdx.x * blockDim.x + threadIdx.x;
  const int stride = gridDim.x * blockDim.x;
  for (; i < n4; i += stride) {
    float4 x = ((const float4*)o)[i];
    float4 y = ((const float4*)b)[i];
    float4 z = {x.x + y.x, x.y + y.y, x.z + y.z, x.w + y.w};
    ((float4*)o)[i] = z;
  }
}

// ------- fused weight transpose+convert: 5 matrices, one launch -------
__global__ void k_wt(const float* __restrict__ Wq, const float* __restrict__ Wk,
                     const float* __restrict__ Wv, const float* __restrict__ Wr,
                     const float* __restrict__ Wo, short* __restrict__ WcatT,
                     short* __restrict__ WoT)
{
  __shared__ float tile[32][33];
  const int id = blockIdx.x;
  const float* src; short* dst; int R, C, Ct, local;
  if (id < 16384)      { src = Wq; dst = WcatT;                      R = 2048; C = 8192; Ct = 256; local = id; }
  else if (id < 18432) { src = Wk; dst = WcatT + (size_t)8192*2048;  R = 2048; C = 1024; Ct =  32; local = id - 16384; }
  else if (id < 20480) { src = Wv; dst = WcatT + (size_t)9216*2048;  R = 2048; C = 1024; Ct =  32; local = id - 18432; }
  else if (id < 21504) { src = Wr; dst = WcatT + (size_t)10240*2048; R = 2048; C =  512; Ct =  16; local = id - 20480; }
  else                 { src = Wo; dst = WoT;                        R = 4096; C = 2048; Ct =  64; local = id - 21504; }
  const int c0 = (local % Ct) * 32, r0 = (local / Ct) * 32;
  const int tx = threadIdx.x, ty = threadIdx.y;   // (32, 8)
  #pragma unroll
  for (int i = ty; i < 32; i += 8)
    tile[i][tx] = src[(size_t)(r0 + i) * C + c0 + tx];
  __syncthreads();
  #pragma unroll
  for (int i = ty; i < 32; i += 8)
    dst[(size_t)(c0 + i) * R + r0 + tx] = f2bf(tile[tx][i]);
}

// ---------------- bf16 V-slice transpose: Ycat v -> VT[b,hk,d,s] ----------------
__global__ void k_vt(const short* __restrict__ Ycat, short* __restrict__ VT){
  __shared__ short tile[32][33];
  int b = blockIdx.z >> 2, hk = blockIdx.z & 3;
  int s0 = blockIdx.x * 32, d0 = blockIdx.y * 32;
  int tx = threadIdx.x, ty = threadIdx.y;   // (32, 8)
  #pragma unroll
  for (int i = ty; i < 32; i += 8)
    tile[i][tx] = Ycat[(size_t)(b * S_LEN + s0 + i) * LW + 9216 + hk * 256 + d0 + tx];
  __syncthreads();
  #pragma unroll
  for (int i = ty; i < 32; i += 8)
    VT[(size_t)((b * NKV + hk) * HDIM + d0 + i) * S_LEN + s0 + tx] = tile[tx][i];
}

// ================= 256x256 8-phase bf16 GEMM (T1+T2+T3/T4+T5) =================
// Read/write swizzle: f(row) = (row>>1)&3 -> 2-way max under 16-lane phasing.
// SPLITK=1: nwg=256; swz>>7 selects K-half; half0 -> C0, half1 -> C1.
// Epilogue: LDS-staged transpose -> coalesced dwordx4 stores (cvt_pk for bf16).
#define MFMA_(a, b, c) __builtin_amdgcn_mfma_f32_16x16x32_bf16(a, b, c, 0, 0, 0)
#define As ((short(*)[2][8192])(SMEM))
#define Bs ((short(*)[2][8192])(SMEM + 32768))
#define LDA_(buf, ks, mh, f) (*(const bf16x8*)&As[buf][ks][(wm*128 + (mh)*64 + (f)*16 + l15) * 32 + rdSlot])
#define LDB_(buf, ks, f)     (*(const bf16x8*)&Bs[buf][ks][(wn*64  + (f)*16 + l15) * 32 + rdSlot])
#define STAGE_A_(buf, ks, tile) { \
  gload16(aG0 + (size_t)(tile)*64 + (ks)*32, &As[buf][ks][w*512]); \
  gload16(aG1 + (size_t)(tile)*64 + (ks)*32, &As[buf][ks][4096 + w*512]); }
#define STAGE_B_(buf, ks, tile) { \
  gload16(bG0 + (size_t)(tile)*64 + (ks)*32, &Bs[buf][ks][w*512]); \
  gload16(bG1 + (size_t)(tile)*64 + (ks)*32, &Bs[buf][ks][4096 + w*512]); }
#define VM4 asm volatile("s_waitcnt vmcnt(4)" ::: "memory");
#define PH_(buf, ks, mh, LB, ...) { \
  bf16x8 a0 = LDA_(buf,ks,mh,0), a1 = LDA_(buf,ks,mh,1), a2 = LDA_(buf,ks,mh,2), a3 = LDA_(buf,ks,mh,3); \
  if (LB) { b0 = LDB_(buf,ks,0); b1 = LDB_(buf,ks,1); b2 = LDB_(buf,ks,2); b3 = LDB_(buf,ks,3); } \
  __VA_ARGS__ \
  __builtin_amdgcn_s_barrier(); \
  asm volatile("s_waitcnt lgkmcnt(0)" ::: "memory"); \
  __builtin_amdgcn_s_setprio(1); \
  acc[(mh)*4+0][0] = MFMA_(a0, b0, acc[(mh)*4+0][0]); \
  acc[(mh)*4+0][1] = MFMA_(a0, b1, acc[(mh)*4+0][1]); \
  acc[(mh)*4+0][2] = MFMA_(a0, b2, acc[(mh)*4+0][2]); \
  acc[(mh)*4+0][3] = MFMA_(a0, b3, acc[(mh)*4+0][3]); \
  acc[(mh)*4+1][0] = MFMA_(a1, b0, acc[(mh)*4+1][0]); \
  acc[(mh)*4+1][1] = MFMA_(a1, b1, acc[(mh)*4+1][1]); \
  acc[(mh)*4+1][2] = MFMA_(a1, b2, acc[(mh)*4+1][2]); \
  acc[(mh)*4+1][3] = MFMA_(a1, b3, acc[(mh)*4+1][3]); \
  acc[(mh)*4+2][0] = MFMA_(a2, b0, acc[(mh)*4+2][0]); \
  acc[(mh)*4+2][1] = MFMA_(a2, b1, acc[(mh)*4+2][1]); \
  acc[(mh)*4+2][2] = MFMA_(a2, b2, acc[(mh)*4+2][2]); \
  acc[(mh)*4+2][3] = MFMA_(a2, b3, acc[(mh)*4+2][3]); \
  acc[(mh)*4+3][0] = MFMA_(a3, b0, acc[(mh)*4+3][0]); \
  acc[(mh)*4+3][1] = MFMA_(a3, b1, acc[(mh)*4+3][1]); \
  acc[(mh)*4+3][2] = MFMA_(a3, b2, acc[(mh)*4+3][2]); \
  acc[(mh)*4+3][3] = MFMA_(a3, b3, acc[(mh)*4+3][3]); \
  __builtin_amdgcn_s_setprio(0); \
  __builtin_amdgcn_s_barrier(); }

template<int OUTF32, int CM, int SPLITK>
__global__ __launch_bounds__(512) void k_gemm2(const short* __restrict__ A,
                                               const short* __restrict__ BT,
                                               void* __restrict__ C0,
                                               void* __restrict__ C1,
                                               int M, int N, int Kpitch, int Klen,
                                               int gx)
{
  __shared__ __align__(16) short SMEM[65536];   // As | Bs ; epilogue: fp32 stage
  const int t = threadIdx.x, lane = t & 63, w = t >> 6;
  const int l15 = lane & 15;
  const int wm = w >> 2, wn = w & 3;
  const int rdSlot = (((lane >> 4) ^ ((lane >> 1) & 3)) * 8);

  // XCD-aware bijective swizzle (nwg % 8 == 0 at all call sites)
  const int nwg = gridDim.x;
  const int swz = (blockIdx.x & 7) * (nwg >> 3) + (blockIdx.x >> 3);
  int rem = swz, kOff = 0;
  void* Cp = C0;
  if (SPLITK) {                 // nwg == 256: top bit selects K-half
    rem = swz & 127;
    if (swz >> 7) { kOff = Klen; Cp = C1; }
  }
  const int m0 = (CM ? (rem % gx) : (rem / gx)) * 256;
  const int n0 = (CM ? (rem / gx) : (rem % gx)) * 256;

  const int sRow = w * 16 + (lane >> 2);
  const int sSwz = ((lane & 3) ^ ((lane >> 3) & 3)) * 8;
  const short* aG0 = A  + (size_t)(m0 + sRow) * Kpitch + kOff + sSwz;
  const short* aG1 = A  + (size_t)(m0 + 128 + sRow) * Kpitch + kOff + sSwz;
  const short* bG0 = BT + (size_t)(n0 + sRow) * Kpitch + kOff + sSwz;
  const short* bG1 = BT + (size_t)(n0 + 128 + sRow) * Kpitch + kOff + sSwz;

  f32x4 acc[8][4] = {};
  bf16x8 b0 = {}, b1 = {}, b2 = {}, b3 = {};

  STAGE_A_(0, 0, 0) STAGE_A_(0, 1, 0) STAGE_B_(0, 0, 0) STAGE_B_(0, 1, 0)
  STAGE_A_(1, 0, 1) STAGE_B_(1, 0, 1)
  asm volatile("s_waitcnt vmcnt(4)" ::: "memory");
  __builtin_amdgcn_s_barrier();

  const int nIt = Klen >> 7;
  for (int i = 0; i < nIt; ++i) {
    const int c = 2 * i;
    const bool st = (i + 1 < nIt);
    PH_(0, 0, 0, 1, STAGE_A_(1, 1, c + 1))
    PH_(0, 0, 1, 0, STAGE_B_(1, 1, c + 1))
    PH_(0, 1, 0, 1, if (st) STAGE_A_(0, 0, c + 2))
    PH_(0, 1, 1, 0, if (st) STAGE_B_(0, 0, c + 2) VM4)
    PH_(1, 0, 0, 1, if (st) STAGE_A_(0, 1, c + 2))
    PH_(1, 0, 1, 0, if (st) STAGE_B_(0, 1, c + 2))
    PH_(1, 1, 0, 1, if (st) STAGE_A_(1, 0, c + 3))
    PH_(1, 1, 1, 0, if (st) STAGE_B_(1, 0, c + 3) VM4)
  }

  // ---- epilogue: LDS transpose (4 chunks of 64 rows x 256 cols, pitch 260) ----
  float* Cl = (float*)SMEM;
  const int g = lane >> 4;
  #pragma unroll
  for (int ch = 0; ch < 4; ++ch) {
    if (wm == (ch >> 1)) {
      #pragma unroll
      for (int ii2 = 0; ii2 < 4; ++ii2)
        #pragma unroll
        for (int j = 0; j < 4; ++j)
          #pragma unroll
          for (int r = 0; r < 4; ++r)
            Cl[(ii2*16 + g*4 + r) * 260 + wn*64 + j*16 + l15] = acc[(ch & 1)*4 + ii2][j][r];
    }
    asm volatile("s_waitcnt lgkmcnt(0)" ::: "memory");
    __builtin_amdgcn_s_barrier();
    #pragma unroll
    for (int p = 0; p < 4; ++p) {
      const int row = (t >> 5) + p * 16;
      const int c8 = (t & 31) * 8;
      f32x4 v0 = *(const f32x4*)&Cl[row * 260 + c8];
      f32x4 v1 = *(const f32x4*)&Cl[row * 260 + c8 + 4];
      const int grow = m0 + ch * 64 + row;
      if (OUTF32) {
        *(f32x4*)&((float*)Cp)[(size_t)grow * N + n0 + c8]     = v0;
        *(f32x4*)&((float*)Cp)[(size_t)grow * N + n0 + c8 + 4] = v1;
      } else {
        unsigned d0, d1, d2, d3;
        asm("v_cvt_pk_bf16_f32 %0, %1, %2" : "=v"(d0) : "v"(v0[0]), "v"(v0[1]));
        asm("v_cvt_pk_bf16_f32 %0, %1, %2" : "=v"(d1) : "v"(v0[2]), "v"(v0[3]));
        asm("v_cvt_pk_bf16_f32 %0, %1, %2" : "=v"(d2) : "v"(v1[0]), "v"(v1[1]));
        asm("v_cvt_pk_bf16_f32 %0, %1, %2" : "=v"(d3) : "v"(v1[2]), "v"(v1[3]));
        uint4 u = {d0, d1, d2, d3};
        *(uint4*)&((short*)Cp)[(size_t)grow * N + n0 + c8] = u;
      }
    }
    asm volatile("s_waitcnt lgkmcnt(0)" ::: "memory");
    __builtin_amdgcn_s_barrier();
  }
}
#undef As
#undef Bs

// ---------------- per-token: RMSNorm(q,k), gates, partial RoPE, in place ----------------
__global__ __launch_bounds__(256) void k_post(short* __restrict__ Ycat,
    const float* __restrict__ cosb, const float* __restrict__ sinb,
    const float* __restrict__ qw, const float* __restrict__ kw)
{
  const int tok = blockIdx.x;                 // b*S + s
  const int lane = threadIdx.x & 63, w = threadIdx.x >> 6;
  const size_t rowb = (size_t)tok * LW;
  const int d0 = lane * 4;

  float gq[4], gv[4];
  {
    s16x4 a  = *(const s16x4*)&Ycat[rowb + 10240 + d0];
    s16x4 bq = *(const s16x4*)&Ycat[rowb + 10240 + 256 + d0];
    #pragma unroll
    for (int j = 0; j < 4; ++j){ gq[j] = sigm(bf2f(a[j])); gv[j] = sigm(bf2f(bq[j])); }
  }
  float c4[4] = {0,0,0,0}, s4[4] = {0,0,0,0};
  if (lane < 16) {
    float4 c = *(const float4*)&cosb[(size_t)tok * 64 + d0];
    float4 s = *(const float4*)&sinb[(size_t)tok * 64 + d0];
    c4[0]=c.x; c4[1]=c.y; c4[2]=c.z; c4[3]=c.w;
    s4[0]=s.x; s4[1]=s.y; s4[2]=s.z; s4[3]=s.w;
  }
  float4 qv4 = *(const float4*)&qw[d0];
  float4 kv4 = *(const float4*)&kw[d0];
  float qwa[4] = {qv4.x, qv4.y, qv4.z, qv4.w};
  float kwa[4] = {kv4.x, kv4.y, kv4.z, kv4.w};

  #pragma unroll
  for (int hi = 0; hi < 4; ++hi) {
    const int hh = w * 4 + hi;
    const size_t off = rowb + hh * 512 + d0;
    s16x4 v = *(const s16x4*)&Ycat[off];
    float x[4];
    #pragma unroll
    for (int j = 0; j < 4; ++j) x[j] = bf2f(v[j]);
    float ss = x[0]*x[0] + x[1]*x[1] + x[2]*x[2] + x[3]*x[3];
    #pragma unroll
    for (int o2 = 1; o2 < 64; o2 <<= 1) ss += __shfl_xor(ss, o2);
    float rr = rsqrtf(ss * (1.0f/256.0f) + 1e-6f);
    #pragma unroll
    for (int j = 0; j < 4; ++j) x[j] = x[j] * rr * (1.0f + qwa[j]) * gq[j];
    float p[4];
    #pragma unroll
    for (int j = 0; j < 4; ++j) p[j] = __shfl_xor(x[j], 8);
    if (lane < 8)       { for (int j = 0; j < 4; ++j) x[j] = x[j]*c4[j] - p[j]*s4[j]; }
    else if (lane < 16) { for (int j = 0; j < 4; ++j) x[j] = x[j]*c4[j] + p[j]*s4[j]; }
    s16x4 o;
    #pragma unroll
    for (int j = 0; j < 4; ++j) o[j] = f2bf(x[j]);
    *(s16x4*)&Ycat[off] = o;
  }
  {
    const size_t off = rowb + 8192 + w * 256 + d0;
    s16x4 v = *(const s16x4*)&Ycat[off];
    float x[4];
    #pragma unroll
    for (int j = 0; j < 4; ++j) x[j] = bf2f(v[j]);
    float ss = x[0]*x[0] + x[1]*x[1] + x[2]*x[2] + x[3]*x[3];
    #pragma unroll
    for (int o2 = 1; o2 < 64; o2 <<= 1) ss += __shfl_xor(ss, o2);
    float rr = rsqrtf(ss * (1.0f/256.0f) + 1e-6f);
    #pragma unroll
    for (int j = 0; j < 4; ++j) x[j] = x[j] * rr * (1.0f + kwa[j]) * gq[j];
    float p[4];
    #pragma unroll
    for (int j = 0; j < 4; ++j) p[j] = __shfl_xor(x[j], 8);
    if (lane < 8)       { for (int j = 0; j < 4; ++j) x[j] = x[j]*c4[j] - p[j]*s4[j]; }
    else if (lane < 16) { for (int j = 0; j < 4; ++j) x[j] = x[j]*c4[j] + p[j]*s4[j]; }
    s16x4 o;
    #pragma unroll
    for (int j = 0; j < 4; ++j) o[j] = f2bf(x[j]);
    *(s16x4*)&Ycat[off] = o;
  }
  {
    const size_t off = rowb + 9216 + w * 256 + d0;
    s16x4 v = *(const s16x4*)&Ycat[off];
    s16x4 o;
    #pragma unroll
    for (int j = 0; j < 4; ++j) o[j] = f2bf(bf2f(v[j]) * gv[j]);
    *(s16x4*)&Ycat[off] = o;
  }
}

// ====== flash attention: swapped operands, per-wave rows, KVBLK=32 dbuf ======
#define ATT_STAGE(bb, jj) { \
  _Pragma("unroll") \
  for (int ri = 0; ri < 4; ++ri) \
    gload16(kSrc + (size_t)((jj) + ri*8) * LW, &Ks[bb][t*8 + ri*2048]); \
  _Pragma("unroll") \
  for (int ri = 0; ri < 4; ++ri) \
    gload16(vSrc + (jj) + (size_t)(ri*64) * S_LEN, &Vs[bb][t*8 + ri*2048]); }

__global__ __launch_bounds__(256) void k_attn(const short* __restrict__ Ycat,
                                              const short* __restrict__ VT,
                                              short* __restrict__ AO)
{
  __shared__ __align__(16) short Ks[2][8192];   // [buf][32 rows x 256]
  __shared__ __align__(16) short Vs[2][8192];   // [buf][256 rows x 32]
  __shared__ __align__(16) short Ps[4][512];    // per-wave [16 rows x 32]

  const int t = threadIdx.x, lane = t & 63, w = t >> 6;
  const int l15 = lane & 15, g = lane >> 4;
  const int id = blockIdx.x;
  const int xcd = id & 7, widx = id >> 3;
  const int b = xcd >> 2, hk = xcd & 3;
  const int h = hk * 4 + (widx & 3);
  const int x = widx >> 2, qq = x & 7, jj = x >> 3;
  const int qsel = (jj == 0) ? 31 - qq : (jj == 1) ? 16 + qq : (jj == 2) ? 15 - qq : qq;
  const int q0 = qsel * 64;
  const int qg = q0 + w * 16 + l15;        // this lane's q-row (global)
  const float SC2 = 0.09016844f;           // 1/16 * log2(e)

  bf16x8 qf[8];
  {
    const size_t qb = ((size_t)(b * S_LEN) + qg) * LW + h * 512 + g * 8;
    #pragma unroll
    for (int kk = 0; kk < 8; ++kk)
      qf[kk] = *(const bf16x8*)&Ycat[qb + kk * 32];
  }
  asm volatile("s_waitcnt vmcnt(0)" ::: "memory");

  const int kRow = t >> 5;
  const int kColS = ((((t & 31) * 16) ^ ((kRow & 7) << 4)) >> 1);
  const int vRow = t >> 2;
  const int vColS = ((((t & 3) * 16) ^ ((vRow & 3) << 4)) >> 1);
  const short* kSrc = Ycat + ((size_t)(b * S_LEN) + kRow) * LW + 8192 + hk * 256 + kColS;
  const short* vSrc = VT + ((size_t)((b * NKV + hk) * HDIM + vRow)) * S_LEN + vColS;

  f32x4 oacc[16] = {};
  float m_r = -1e30f, l_r = 0.0f;

  const int nt = (q0 >> 5) + 2;
  ATT_STAGE(0, 0)
  int buf = 0;
  char* Pw = (char*)Ps[w] + l15 * 64;
  const int pswz = (l15 & 3) << 4;

  for (int ti = 0; ti < nt; ++ti) {
    const int j0 = ti * 32;
    const int jn = (ti + 1 < nt) ? j0 + 32 : 0;   // dummy re-stage keeps vmcnt uniform
    ATT_STAGE(buf ^ 1, jn)
    asm volatile("s_waitcnt vmcnt(8)" ::: "memory");
    __builtin_amdgcn_s_barrier();

    if (j0 <= q0 + w * 16 + 15) {                 // wave-uniform causal skip
      f32x4 sa[2] = {};
      #pragma unroll
      for (int kk = 0; kk < 8; ++kk) {
        #pragma unroll
        for (int c = 0; c < 2; ++c) {
          const int row = c * 16 + l15;
          bf16x8 kf = *(const bf16x8*)((const char*)Ks[buf] + row * 512
                       + ((kk * 64 + g * 16) ^ ((l15 & 7) << 4)));
          sa[c] = __builtin_amdgcn_mfma_f32_16x16x32_bf16(kf, qf[kk], sa[c], 0, 0, 0);
        }
      }
      float s[8];
      #pragma unroll
      for (int c = 0; c < 2; ++c)
        #pragma unroll
        for (int r = 0; r < 4; ++r) s[c * 4 + r] = sa[c][r];
      if (j0 + 31 > qg) {
        #pragma unroll
        for (int c = 0; c < 2; ++c)
          #pragma unroll
          for (int r = 0; r < 4; ++r)
            if (j0 + c * 16 + g * 4 + r > qg) s[c * 4 + r] = -1e30f;
      }
      float mx = s[0];
      #pragma unroll
      for (int i = 1; i < 8; ++i) mx = fmaxf(mx, s[i]);
      mx = fmaxf(mx, __shfl_xor(mx, 16));
      mx = fmaxf(mx, __shfl_xor(mx, 32));
      if (!__all(mx - m_r <= 128.0f)) {           // T13 defer-max
        const float mnew = fmaxf(m_r, mx);
        const float alpha = exp2f((m_r - mnew) * SC2);
        l_r *= alpha;
        #pragma unroll
        for (int jb = 0; jb < 16; ++jb)
          #pragma unroll
          for (int r = 0; r < 4; ++r) oacc[jb][r] *= alpha;
        m_r = mnew;
      }
      float p[8], rs = 0.0f;
      #pragma unroll
      for (int i = 0; i < 8; ++i) { p[i] = exp2f((s[i] - m_r) * SC2); rs += p[i]; }
      rs += __shfl_xor(rs, 16);
      rs += __shfl_xor(rs, 32);
      l_r += rs;
      #pragma unroll
      for (int c = 0; c < 2; ++c) {
        uint2 u;
        u.x = (unsigned short)f2bf(p[c*4+0]) | ((unsigned)(unsigned short)f2bf(p[c*4+1]) << 16);
        u.y = (unsigned short)f2bf(p[c*4+2]) | ((unsigned)(unsigned short)f2bf(p[c*4+3]) << 16);
        *(uint2*)(Pw + ((c * 32 + 8 * g) ^ pswz)) = u;
      }
      bf16x8 pa = *(const bf16x8*)(Pw + ((16 * g) ^ pswz));   // keys g*8..+7
      #pragma unroll
      for (int jb = 0; jb < 16; ++jb) {
        const int vrow = jb * 16 + l15;
        bf16x8 vf = *(const bf16x8*)((const char*)Vs[buf] + vrow * 64
                     + ((16 * g) ^ ((l15 & 3) << 4)));
        oacc[jb] = __builtin_amdgcn_mfma_f32_16x16x32_bf16(vf, pa, oacc[jb], 0, 0, 0);
      }
    }
    __builtin_amdgcn_s_barrier();
    buf ^= 1;
  }
  asm volatile("s_waitcnt vmcnt(0)" ::: "memory");  // drain dummy stage

  const float linv = 1.0f / l_r;
  const size_t gb = ((size_t)(b * S_LEN) + qg) * LW + h * 512 + 256;
  const size_t ob = ((size_t)(b * S_LEN) + qg) * 4096 + h * 256;
  #pragma unroll
  for (int jb = 0; jb < 16; ++jb) {
    const int d0 = jb * 16 + g * 4;
    s16x4 gt = *(const s16x4*)&Ycat[gb + d0];
    s16x4 o;
    #pragma unroll
    for (int r = 0; r < 4; ++r)
      o[r] = f2bf(oacc[jb][r] * linv * sigm(bf2f(gt[r])));
    *(s16x4*)&AO[ob + d0] = o;
  }
}

extern "C" void kernel_launch(void* const* d_in, const int* in_sizes, int n_in,
                              void* d_out, int out_size, void* d_ws, size_t ws_size,
                              hipStream_t stream) {
  const float* X    = (const float*)d_in[0];
  const float* cosb = (const float*)d_in[1];
  const float* sinb = (const float*)d_in[2];
  const float* Wq   = (const float*)d_in[4];
  const float* Wk   = (const float*)d_in[5];
  const float* Wv   = (const float*)d_in[6];
  const float* Wo   = (const float*)d_in[7];
  const float* qw   = (const float*)d_in[8];
  const float* kw   = (const float*)d_in[9];
  const float* Wr   = (const float*)d_in[10];

  short* Xb    = (short*)d_ws;                       //  8,388,608
  short* WcatT = Xb    +  8388608;                   // 22,020,096
  short* AO    = WcatT;                              // alias (dead after GEMM0)
  short* WoT   = WcatT + 22020096;                   //  8,388,608
  short* Ycat  = WoT   +  8388608;                   // 44,040,192
  short* VT    = Ycat  + 44040192;                   //  4,194,304
  float* P1    = (float*)Ycat;                       // split-K partial (Ycat dead then)

  dim3 tb(32, 8);
  k_cvt<<<8192, 256, 0, stream>>>(X, Xb, 2097152);
  k_wt<<<29696, tb, 0, stream>>>(Wq, Wk, Wv, Wr, Wo, WcatT, WoT);

  k_gemm2<0, 1, 0><<<672, 512, 0, stream>>>(Xb, WcatT, Ycat, nullptr,
                                            4096, 10752, 2048, 2048, 16);
  k_post<<<4096, 256, 0, stream>>>(Ycat, cosb, sinb, qw, kw);
  k_vt<<<dim3(64, 8, 8), tb, 0, stream>>>(Ycat, VT);
  k_attn<<<1024, 256, 0, stream>>>(Ycat, VT, AO);
  k_gemm2<1, 0, 1><<<256, 512, 0, stream>>>(AO, WoT, d_out, P1,
                                            4096, 2048, 4096, 2048, 8);
  // d_out has 4096*2048 = 8,388,608 floats = 2,097,152 float4s  (R5 bug: was 2x)
  k_add<<<2048, 256, 0, stream>>>(P1, (float*)d_out, 2097152);
}